// Round 1
// baseline (542.367 us; speedup 1.0000x reference)
//
#include <hip/hip_runtime.h>
#include <math.h>

#define DD 1024
#define NB 16

typedef unsigned short u16;
typedef __attribute__((ext_vector_type(8))) short short8;
typedef __attribute__((ext_vector_type(4))) float f32x4;

__device__ __forceinline__ float gelu_f(float x) {
  return 0.5f * x * (1.0f + erff(x * 0.70710678118654752440f));
}
__device__ __forceinline__ u16 f2bf(float f) {
  union { float f; unsigned u; } v; v.f = f;
  return (u16)((v.u + 0x7FFFu + ((v.u >> 16) & 1u)) >> 16);
}
__device__ __forceinline__ float bf2f(u16 b) {
  union { unsigned u; float f; } v; v.u = ((unsigned)b) << 16;
  return v.f;
}

// ---------------- x (f32) -> bf16 ----------------
__launch_bounds__(256)
__global__ void cvt_kernel(const float* __restrict__ x, u16* __restrict__ xb) {
  size_t i = (size_t)blockIdx.x * 256 + threadIdx.x;   // each thread: 8 elements
  const float4* xf = (const float4*)x;
  float4 v0 = xf[i * 2], v1 = xf[i * 2 + 1];
  short8 o;
  o[0] = (short)f2bf(v0.x); o[1] = (short)f2bf(v0.y);
  o[2] = (short)f2bf(v0.z); o[3] = (short)f2bf(v0.w);
  o[4] = (short)f2bf(v1.x); o[5] = (short)f2bf(v1.y);
  o[6] = (short)f2bf(v1.z); o[7] = (short)f2bf(v1.w);
  *(short8*)(xb + i * 8) = o;
}

// ---------------- LayerNorm over ada_emb rows ----------------
__launch_bounds__(256)
__global__ void ln_kernel(const float* __restrict__ ada, const float* __restrict__ gamma,
                          const float* __restrict__ beta, float* __restrict__ c) {
  int b = blockIdx.x;
  int t = threadIdx.x;
  const float* row = ada + b * DD;
  float s = 0.f, s2 = 0.f;
  for (int i = t; i < DD; i += 256) { float v = row[i]; s += v; s2 += v * v; }
  for (int off = 32; off; off >>= 1) { s += __shfl_down(s, off); s2 += __shfl_down(s2, off); }
  __shared__ float rs[4], rs2[4];
  int wave = t >> 6, lane = t & 63;
  if (lane == 0) { rs[wave] = s; rs2[wave] = s2; }
  __syncthreads();
  if (t == 0) {
    float a = 0.f, a2 = 0.f;
    for (int w = 0; w < 4; w++) { a += rs[w]; a2 += rs2[w]; }
    rs[0] = a * (1.0f / DD); rs2[0] = a2 * (1.0f / DD);
  }
  __syncthreads();
  float mu = rs[0];
  float var = rs2[0] - mu * mu;
  float inv = rsqrtf(var + 1e-5f);
  for (int i = t; i < DD; i += 256)
    c[b * DD + i] = (row[i] - mu) * inv * gamma[i] + beta[i];
}

// ---------------- h = gelu(c @ W1 + bias1) ----------------
__launch_bounds__(256)
__global__ void h_kernel(const float* __restrict__ c, const float* __restrict__ W1,
                         const float* __restrict__ bias1, float* __restrict__ h) {
  int b = blockIdx.y;
  int i = blockIdx.x * 256 + threadIdx.x;
  __shared__ float cs[DD];
  for (int a = threadIdx.x; a < DD; a += 256) cs[a] = c[b * DD + a];
  __syncthreads();
  float acc = bias1[i];
  #pragma unroll 4
  for (int a = 0; a < DD; a++) acc += cs[a] * W1[(size_t)a * DD + i];
  h[b * DD + i] = gelu_f(acc);
}

// ---------------- w = h @ W2 + bias2  (16 x 32768) ----------------
__launch_bounds__(128)
__global__ void w_kernel(const float* __restrict__ h, const float* __restrict__ W2,
                         const float* __restrict__ bias2, float* __restrict__ w) {
  int j = blockIdx.x * 128 + threadIdx.x;   // 0..32767, grid.x = 256
  int t = threadIdx.x;
  float acc[NB];
  float bs = bias2[j];
  #pragma unroll
  for (int b = 0; b < NB; b++) acc[b] = bs;
  __shared__ float hl[256][NB];   // 16 KB
  for (int a0 = 0; a0 < DD; a0 += 256) {
    __syncthreads();
    for (int a = t; a < 256; a += 128)
      for (int b = 0; b < NB; b++) hl[a][b] = h[b * DD + a0 + a];
    __syncthreads();
    #pragma unroll 4
    for (int al = 0; al < 256; al++) {
      float w2 = W2[(size_t)(a0 + al) * 32768 + j];
      #pragma unroll
      for (int b = 0; b < NB; b++) acc[b] += hl[al][b] * w2;
    }
  }
  #pragma unroll
  for (int b = 0; b < NB; b++) w[(size_t)b * 32768 + j] = acc[b];
}

// ---------------- transpose base_down (f32 1024x1024) ----------------
__launch_bounds__(256)
__global__ void transpose_kernel(const float* __restrict__ in, float* __restrict__ out) {
  __shared__ float tile[32][33];
  int bx = blockIdx.x * 32, by = blockIdx.y * 32;
  int tx = threadIdx.x & 31, ty = threadIdx.x >> 5;   // 32 x 8
  for (int r = ty; r < 32; r += 8) tile[r][tx] = in[(size_t)(by + r) * DD + bx + tx];
  __syncthreads();
  for (int r = ty; r < 32; r += 8) out[(size_t)(bx + r) * DD + by + tx] = tile[tx][r];
}

// ---- fold WdT[b][l][d] = base_downT[l][d] + sum_r a2[d][r]*b2[l][r] (bf16) ----
// a2[d][r] = w[b][16384 + d*8 + r]; b2[l][r] = w[b][24576 + l*8 + r]
__launch_bounds__(256)
__global__ void fold_down_kernel(const float* __restrict__ bdT, const float* __restrict__ w,
                                 u16* __restrict__ wt) {
  int b = blockIdx.y;
  const float* wb = w + (size_t)b * 32768;
  size_t base = (size_t)b << 20;
  int idx8 = blockIdx.x * 256 + threadIdx.x;   // grid.x = 512 -> 131072 per batch
  int l = idx8 >> 7;
  int d0 = (idx8 & 127) << 3;
  float b2v[8];
  #pragma unroll
  for (int r = 0; r < 8; r++) b2v[r] = wb[24576 + l * 8 + r];
  short8 ov;
  #pragma unroll
  for (int jj = 0; jj < 8; jj++) {
    int d = d0 + jj;
    float acc = bdT[(size_t)l * DD + d];
    const float* a2 = wb + 16384 + d * 8;
    #pragma unroll
    for (int r = 0; r < 8; r++) acc += a2[r] * b2v[r];
    ov[jj] = (short)f2bf(acc);
  }
  *(short8*)(wt + base + (size_t)l * DD + d0) = ov;
}

// ---- fold WuT[b][k][l] = base_up[k][l] + sum_r a1[k][r]*b1[l][r] (bf16) ----
// a1[k][r] = w[b][k*8 + r]; b1[l][r] = w[b][8192 + l*8 + r]
__launch_bounds__(256)
__global__ void fold_up_kernel(const float* __restrict__ bu, const float* __restrict__ w,
                               u16* __restrict__ wt) {
  int b = blockIdx.y;
  const float* wb = w + (size_t)b * 32768;
  size_t base = (size_t)b << 20;
  int idx8 = blockIdx.x * 256 + threadIdx.x;
  int k = idx8 >> 7;
  int l0 = (idx8 & 127) << 3;
  float a1v[8];
  #pragma unroll
  for (int r = 0; r < 8; r++) a1v[r] = wb[k * 8 + r];
  short8 ov;
  #pragma unroll
  for (int jj = 0; jj < 8; jj++) {
    int l = l0 + jj;
    float acc = bu[(size_t)k * DD + l];
    const float* b1 = wb + 8192 + l * 8;
    #pragma unroll
    for (int r = 0; r < 8; r++) acc += b1[r] * a1v[r];
    ov[jj] = (short)f2bf(acc);
  }
  *(short8*)(wt + base + (size_t)k * DD + l0) = ov;
}

// ---------------- batched GEMM: C = A(bf16) @ BT(bf16)^T, 128x128 tile ----------------
// PHASE 1: C = gelu(A@B) -> bf16 mid.  PHASE 2: C = resid + A@B -> f32 out.
template<int PHASE>
__launch_bounds__(256)
__global__ void gemm_kernel(const u16* __restrict__ A, const u16* __restrict__ BT,
                            const u16* __restrict__ resid, void* __restrict__ Cout) {
  constexpr int BK = 64;
  __shared__ __align__(16) u16 As[128 * BK];
  __shared__ __align__(16) u16 Bs[128 * BK];
  int b = blockIdx.z;
  int tm = blockIdx.y, tn = blockIdx.x;
  const u16* Ab = A + ((size_t)b << 20) + (size_t)(tm * 128) * DD;
  const u16* Bb = BT + ((size_t)b << 20) + (size_t)(tn * 128) * DD;
  int t = threadIdx.x, lane = t & 63, g = lane >> 4, l15 = lane & 15;
  int wave = t >> 6, wm = wave >> 1, wn = wave & 1;

  // staging map: chunk = c*256 + t covers 16B; row m = chunk>>3; swizzled col (elements)
  int sm[4], sq[4];
  #pragma unroll
  for (int c = 0; c < 4; c++) {
    int chunk = c * 256 + t;
    sm[c] = chunk >> 3;
    sq[c] = ((((chunk & 7) << 4) ^ ((sm[c] & 7) << 4)) >> 1);   // element offset in row
  }

  f32x4 acc[4][4] = {};

  for (int ks = 0; ks < DD; ks += BK) {
    short8 va[4], vb[4];
    #pragma unroll
    for (int c = 0; c < 4; c++) {
      va[c] = *(const short8*)(Ab + (size_t)sm[c] * DD + ks + sq[c]);
      vb[c] = *(const short8*)(Bb + (size_t)sm[c] * DD + ks + sq[c]);
    }
    #pragma unroll
    for (int c = 0; c < 4; c++) {
      *(short8*)(As + (c * 256 + t) * 8) = va[c];
      *(short8*)(Bs + (c * 256 + t) * 8) = vb[c];
    }
    __syncthreads();
    #pragma unroll
    for (int kk = 0; kk < 2; kk++) {
      short8 af[4], bf[4];
      #pragma unroll
      for (int i = 0; i < 4; i++) {
        int row = wm * 64 + i * 16 + l15;
        int e = (kk * 32 + g * 8) ^ ((row & 7) << 3);
        af[i] = *(const short8*)(As + row * BK + e);
      }
      #pragma unroll
      for (int j = 0; j < 4; j++) {
        int row = wn * 64 + j * 16 + l15;
        int e = (kk * 32 + g * 8) ^ ((row & 7) << 3);
        bf[j] = *(const short8*)(Bs + row * BK + e);
      }
      #pragma unroll
      for (int i = 0; i < 4; i++)
        #pragma unroll
        for (int j = 0; j < 4; j++)
          acc[i][j] = __builtin_amdgcn_mfma_f32_16x16x32_bf16(af[i], bf[j], acc[i][j], 0, 0, 0);
    }
    __syncthreads();
  }

  int r0 = tm * 128 + wm * 64, c0 = tn * 128 + wn * 64;
  if (PHASE == 1) {
    u16* mid = (u16*)Cout + ((size_t)b << 20);
    #pragma unroll
    for (int i = 0; i < 4; i++)
      #pragma unroll
      for (int j = 0; j < 4; j++)
        #pragma unroll
        for (int r = 0; r < 4; r++) {
          int row = r0 + i * 16 + g * 4 + r;
          int col = c0 + j * 16 + l15;
          mid[(size_t)row * DD + col] = f2bf(gelu_f(acc[i][j][r]));
        }
  } else {
    float* out = (float*)Cout + ((size_t)b << 20);
    const u16* xb = resid + ((size_t)b << 20);
    #pragma unroll
    for (int i = 0; i < 4; i++)
      #pragma unroll
      for (int j = 0; j < 4; j++)
        #pragma unroll
        for (int r = 0; r < 4; r++) {
          int row = r0 + i * 16 + g * 4 + r;
          int col = c0 + j * 16 + l15;
          size_t idx = (size_t)row * DD + col;
          out[idx] = bf2f(xb[idx]) + acc[i][j][r];
        }
  }
}

extern "C" void kernel_launch(void* const* d_in, const int* in_sizes, int n_in,
                              void* d_out, int out_size, void* d_ws, size_t ws_size,
                              hipStream_t stream) {
  const float* x         = (const float*)d_in[0];
  const float* ada       = (const float*)d_in[1];
  const float* base_up   = (const float*)d_in[2];
  const float* base_down = (const float*)d_in[3];
  const float* gamma     = (const float*)d_in[4];
  const float* beta      = (const float*)d_in[5];
  const float* W1        = (const float*)d_in[6];
  const float* bias1     = (const float*)d_in[7];
  const float* W2        = (const float*)d_in[8];
  const float* bias2     = (const float*)d_in[9];
  float* out = (float*)d_out;
  char* ws = (char*)d_ws;

  float* c   = (float*)(ws);                 // 64 KB
  float* h   = (float*)(ws + 0x10000);       // 64 KB
  float* w   = (float*)(ws + 0x20000);       // 2 MB
  float* bdT = (float*)(ws + 0x220000);      // 4 MB
  u16*   xb  = (u16*)  (ws + 0x620000);      // 32 MB
  u16*   wt  = (u16*)  (ws + 0x2620000);     // 32 MB (WdT, then reused for WuT)
  u16*   mid = (u16*)  (ws + 0x4620000);     // 32 MB  (total ~102 MB)

  cvt_kernel<<<dim3(8192), dim3(256), 0, stream>>>(x, xb);
  ln_kernel<<<dim3(16), dim3(256), 0, stream>>>(ada, gamma, beta, c);
  h_kernel<<<dim3(4, 16), dim3(256), 0, stream>>>(c, W1, bias1, h);
  w_kernel<<<dim3(256), dim3(128), 0, stream>>>(h, W2, bias2, w);
  transpose_kernel<<<dim3(32, 32), dim3(256), 0, stream>>>(base_down, bdT);
  fold_down_kernel<<<dim3(512, 16), dim3(256), 0, stream>>>(bdT, w, wt);
  gemm_kernel<1><<<dim3(8, 8, 16), dim3(256), 0, stream>>>(xb, wt, (const u16*)nullptr, (void*)mid);
  fold_up_kernel<<<dim3(512, 16), dim3(256), 0, stream>>>(base_up, w, wt);
  gemm_kernel<2><<<dim3(8, 8, 16), dim3(256), 0, stream>>>(mid, wt, xb, (void*)out);
}

// Round 2
// 449.921 us; speedup vs baseline: 1.2055x; 1.2055x over previous
//
#include <hip/hip_runtime.h>
#include <math.h>

#define DD 1024
#define NB 16
#define WSPLIT 16

typedef unsigned short u16;
typedef __attribute__((ext_vector_type(8))) short short8;
typedef __attribute__((ext_vector_type(4))) float f32x4;

__device__ __forceinline__ float gelu_f(float x) {
  return 0.5f * x * (1.0f + erff(x * 0.70710678118654752440f));
}
__device__ __forceinline__ u16 f2bf(float f) {
  union { float f; unsigned u; } v; v.f = f;
  return (u16)((v.u + 0x7FFFu + ((v.u >> 16) & 1u)) >> 16);
}
__device__ __forceinline__ float bf2f(u16 b) {
  union { unsigned u; float f; } v; v.u = ((unsigned)b) << 16;
  return v.f;
}
__device__ __forceinline__ void gload_lds16(const u16* g, u16* l) {
  __builtin_amdgcn_global_load_lds(
      (const __attribute__((address_space(1))) void*)g,
      (__attribute__((address_space(3))) void*)l, 16, 0, 0);
}

// ---------------- x (f32) -> bf16 ----------------
__launch_bounds__(256)
__global__ void cvt_kernel(const float* __restrict__ x, u16* __restrict__ xb) {
  size_t i = (size_t)blockIdx.x * 256 + threadIdx.x;   // each thread: 8 elements
  const float4* xf = (const float4*)x;
  float4 v0 = xf[i * 2], v1 = xf[i * 2 + 1];
  short8 o;
  o[0] = (short)f2bf(v0.x); o[1] = (short)f2bf(v0.y);
  o[2] = (short)f2bf(v0.z); o[3] = (short)f2bf(v0.w);
  o[4] = (short)f2bf(v1.x); o[5] = (short)f2bf(v1.y);
  o[6] = (short)f2bf(v1.z); o[7] = (short)f2bf(v1.w);
  *(short8*)(xb + i * 8) = o;
}

// ---------------- LayerNorm over ada_emb rows ----------------
__launch_bounds__(256)
__global__ void ln_kernel(const float* __restrict__ ada, const float* __restrict__ gamma,
                          const float* __restrict__ beta, float* __restrict__ c) {
  int b = blockIdx.x;
  int t = threadIdx.x;
  const float* row = ada + b * DD;
  float s = 0.f, s2 = 0.f;
  for (int i = t; i < DD; i += 256) { float v = row[i]; s += v; s2 += v * v; }
  for (int off = 32; off; off >>= 1) { s += __shfl_down(s, off); s2 += __shfl_down(s2, off); }
  __shared__ float rs[4], rs2[4];
  int wave = t >> 6, lane = t & 63;
  if (lane == 0) { rs[wave] = s; rs2[wave] = s2; }
  __syncthreads();
  if (t == 0) {
    float a = 0.f, a2 = 0.f;
    for (int w = 0; w < 4; w++) { a += rs[w]; a2 += rs2[w]; }
    rs[0] = a * (1.0f / DD); rs2[0] = a2 * (1.0f / DD);
  }
  __syncthreads();
  float mu = rs[0];
  float var = rs2[0] - mu * mu;
  float inv = rsqrtf(var + 1e-5f);
  for (int i = t; i < DD; i += 256)
    c[b * DD + i] = (row[i] - mu) * inv * gamma[i] + beta[i];
}

// ---------------- h = gelu(c @ W1 + bias1) ----------------
__launch_bounds__(256)
__global__ void h_kernel(const float* __restrict__ c, const float* __restrict__ W1,
                         const float* __restrict__ bias1, float* __restrict__ h) {
  int b = blockIdx.y;
  int i = blockIdx.x * 256 + threadIdx.x;
  __shared__ float cs[DD];
  for (int a = threadIdx.x; a < DD; a += 256) cs[a] = c[b * DD + a];
  __syncthreads();
  float acc = bias1[i];
  #pragma unroll 4
  for (int a = 0; a < DD; a++) acc += cs[a] * W1[(size_t)a * DD + i];
  h[b * DD + i] = gelu_f(acc);
}

// ------- w partials: split-K over W2 (16 splits of 64), float4 columns -------
// part[s][b][j] += h[b][k0..k0+64) . W2[k0..k0+64)[j]
__launch_bounds__(256)
__global__ void w_part_kernel(const float* __restrict__ h, const float* __restrict__ W2,
                              float* __restrict__ part) {
  int s = blockIdx.y;                          // k-split
  int j4 = blockIdx.x * 256 + threadIdx.x;     // float4 column index, 0..8191
  int k0 = s * 64;
  int t = threadIdx.x;
  __shared__ float hl[NB][64];                 // 4 KB
  for (int i = t; i < NB * 64; i += 256) hl[i >> 6][i & 63] = h[(size_t)(i >> 6) * DD + k0 + (i & 63)];
  __syncthreads();
  float4 acc[NB];
  #pragma unroll
  for (int b = 0; b < NB; b++) acc[b] = float4{0.f, 0.f, 0.f, 0.f};
  const float4* W2v = (const float4*)W2;       // row stride 8192 float4
  #pragma unroll 4
  for (int al = 0; al < 64; al++) {
    float4 wv = W2v[(size_t)(k0 + al) * 8192 + j4];
    #pragma unroll
    for (int b = 0; b < NB; b++) {
      float hb = hl[b][al];
      acc[b].x += hb * wv.x; acc[b].y += hb * wv.y;
      acc[b].z += hb * wv.z; acc[b].w += hb * wv.w;
    }
  }
  float4* pv = (float4*)part;
  #pragma unroll
  for (int b = 0; b < NB; b++)
    pv[((size_t)s * NB + b) * 8192 + j4] = acc[b];
}

// ------- w = sum_s part[s] + bias2 -------
__launch_bounds__(256)
__global__ void w_reduce_kernel(const float* __restrict__ part, const float* __restrict__ bias2,
                                float* __restrict__ w) {
  int idx = blockIdx.x * 256 + threadIdx.x;    // b*32768 + j, grid 2048
  int j = idx & 32767;
  float acc = bias2[j];
  #pragma unroll
  for (int s = 0; s < WSPLIT; s++) acc += part[(size_t)s * NB * 32768 + idx];
  w[idx] = acc;
}

// ---------------- transpose base_down (f32 1024x1024) ----------------
__launch_bounds__(256)
__global__ void transpose_kernel(const float* __restrict__ in, float* __restrict__ out) {
  __shared__ float tile[32][33];
  int bx = blockIdx.x * 32, by = blockIdx.y * 32;
  int tx = threadIdx.x & 31, ty = threadIdx.x >> 5;   // 32 x 8
  for (int r = ty; r < 32; r += 8) tile[r][tx] = in[(size_t)(by + r) * DD + bx + tx];
  __syncthreads();
  for (int r = ty; r < 32; r += 8) out[(size_t)(bx + r) * DD + by + tx] = tile[tx][r];
}

// ---- fold WdT[b][l][d] = base_downT[l][d] + sum_r a2[d][r]*b2[l][r] (bf16) ----
__launch_bounds__(256)
__global__ void fold_down_kernel(const float* __restrict__ bdT, const float* __restrict__ w,
                                 u16* __restrict__ wt) {
  int b = blockIdx.y;
  const float* wb = w + (size_t)b * 32768;
  size_t base = (size_t)b << 20;
  int idx8 = blockIdx.x * 256 + threadIdx.x;
  int l = idx8 >> 7;
  int d0 = (idx8 & 127) << 3;
  float b2v[8];
  #pragma unroll
  for (int r = 0; r < 8; r++) b2v[r] = wb[24576 + l * 8 + r];
  short8 ov;
  #pragma unroll
  for (int jj = 0; jj < 8; jj++) {
    int d = d0 + jj;
    float acc = bdT[(size_t)l * DD + d];
    const float* a2 = wb + 16384 + d * 8;
    #pragma unroll
    for (int r = 0; r < 8; r++) acc += a2[r] * b2v[r];
    ov[jj] = (short)f2bf(acc);
  }
  *(short8*)(wt + base + (size_t)l * DD + d0) = ov;
}

// ---- fold WuT[b][k][l] = base_up[k][l] + sum_r a1[k][r]*b1[l][r] (bf16) ----
__launch_bounds__(256)
__global__ void fold_up_kernel(const float* __restrict__ bu, const float* __restrict__ w,
                               u16* __restrict__ wt) {
  int b = blockIdx.y;
  const float* wb = w + (size_t)b * 32768;
  size_t base = (size_t)b << 20;
  int idx8 = blockIdx.x * 256 + threadIdx.x;
  int k = idx8 >> 7;
  int l0 = (idx8 & 127) << 3;
  float a1v[8];
  #pragma unroll
  for (int r = 0; r < 8; r++) a1v[r] = wb[k * 8 + r];
  short8 ov;
  #pragma unroll
  for (int jj = 0; jj < 8; jj++) {
    int l = l0 + jj;
    float acc = bu[(size_t)k * DD + l];
    const float* b1 = wb + 8192 + l * 8;
    #pragma unroll
    for (int r = 0; r < 8; r++) acc += b1[r] * a1v[r];
    ov[jj] = (short)f2bf(acc);
  }
  *(short8*)(wt + base + (size_t)k * DD + l0) = ov;
}

// ------------- batched GEMM: C = A(bf16) @ BT(bf16)^T, 128x128 tile -------------
// global_load_lds(16B) staging, linear LDS + pre-swizzled SOURCE + swizzled ds_read.
// PHASE 1: C = gelu(A@B) -> bf16 mid.  PHASE 2: C = resid + A@B -> f32 out.
template<int PHASE>
__launch_bounds__(256)
__global__ void gemm_kernel(const u16* __restrict__ A, const u16* __restrict__ BT,
                            const u16* __restrict__ resid, void* __restrict__ Cout) {
  constexpr int BK = 64;
  __shared__ __align__(16) u16 As[128 * BK];
  __shared__ __align__(16) u16 Bs[128 * BK];
  int b = blockIdx.z;
  int tm = blockIdx.y, tn = blockIdx.x;
  const u16* Ab = A + ((size_t)b << 20) + (size_t)(tm * 128) * DD;
  const u16* Bb = BT + ((size_t)b << 20) + (size_t)(tn * 128) * DD;
  int t = threadIdx.x, lane = t & 63, g = lane >> 4, l15 = lane & 15;
  int wave = t >> 6, wm = wave >> 1, wn = wave & 1;

  // staging precompute: per wave, 4 chunks of 1 KB each (wave-uniform LDS dest,
  // per-lane pre-swizzled global source). swizzle: LDS[row][c8*8+j] = G[row][(c8^(row&7))*8+j]
  int srow[4], se[4], woff[4];
  #pragma unroll
  for (int c = 0; c < 4; c++) {
    woff[c] = (wave * 4 + c) * 1024;           // byte offset of wave chunk
    int off = woff[c] + lane * 16;             // this lane's LDS byte slot
    int row = off >> 7;
    int c8 = (off >> 4) & 7;
    srow[c] = row;
    se[c] = (c8 ^ (row & 7)) << 3;             // element offset in global row
  }

  f32x4 acc[4][4] = {};

  for (int ks = 0; ks < DD; ks += BK) {
    #pragma unroll
    for (int c = 0; c < 4; c++) {
      gload_lds16(Ab + (size_t)srow[c] * DD + ks + se[c], (u16*)((char*)As + woff[c]));
      gload_lds16(Bb + (size_t)srow[c] * DD + ks + se[c], (u16*)((char*)Bs + woff[c]));
    }
    __syncthreads();
    #pragma unroll
    for (int kk = 0; kk < 2; kk++) {
      short8 af[4], bf[4];
      #pragma unroll
      for (int i = 0; i < 4; i++) {
        int row = wm * 64 + i * 16 + l15;
        int e = (kk * 32 + g * 8) ^ ((row & 7) << 3);
        af[i] = *(const short8*)(As + row * BK + e);
      }
      #pragma unroll
      for (int j = 0; j < 4; j++) {
        int row = wn * 64 + j * 16 + l15;
        int e = (kk * 32 + g * 8) ^ ((row & 7) << 3);
        bf[j] = *(const short8*)(Bs + row * BK + e);
      }
      #pragma unroll
      for (int i = 0; i < 4; i++)
        #pragma unroll
        for (int j = 0; j < 4; j++)
          acc[i][j] = __builtin_amdgcn_mfma_f32_16x16x32_bf16(af[i], bf[j], acc[i][j], 0, 0, 0);
    }
    __syncthreads();
  }

  int r0 = tm * 128 + wm * 64, c0 = tn * 128 + wn * 64;
  if (PHASE == 1) {
    u16* mid = (u16*)Cout + ((size_t)b << 20);
    #pragma unroll
    for (int i = 0; i < 4; i++)
      #pragma unroll
      for (int j = 0; j < 4; j++)
        #pragma unroll
        for (int r = 0; r < 4; r++) {
          int row = r0 + i * 16 + g * 4 + r;
          int col = c0 + j * 16 + l15;
          mid[(size_t)row * DD + col] = f2bf(gelu_f(acc[i][j][r]));
        }
  } else {
    float* out = (float*)Cout + ((size_t)b << 20);
    const u16* xb = resid + ((size_t)b << 20);
    #pragma unroll
    for (int i = 0; i < 4; i++)
      #pragma unroll
      for (int j = 0; j < 4; j++)
        #pragma unroll
        for (int r = 0; r < 4; r++) {
          int row = r0 + i * 16 + g * 4 + r;
          int col = c0 + j * 16 + l15;
          size_t idx = (size_t)row * DD + col;
          out[idx] = bf2f(xb[idx]) + acc[i][j][r];
        }
  }
}

extern "C" void kernel_launch(void* const* d_in, const int* in_sizes, int n_in,
                              void* d_out, int out_size, void* d_ws, size_t ws_size,
                              hipStream_t stream) {
  const float* x         = (const float*)d_in[0];
  const float* ada       = (const float*)d_in[1];
  const float* base_up   = (const float*)d_in[2];
  const float* base_down = (const float*)d_in[3];
  const float* gamma     = (const float*)d_in[4];
  const float* beta      = (const float*)d_in[5];
  const float* W1        = (const float*)d_in[6];
  const float* bias1     = (const float*)d_in[7];
  const float* W2        = (const float*)d_in[8];
  const float* bias2     = (const float*)d_in[9];
  float* out = (float*)d_out;
  char* ws = (char*)d_ws;

  float* c    = (float*)(ws);                 // 64 KB
  float* h    = (float*)(ws + 0x10000);       // 64 KB
  float* w    = (float*)(ws + 0x20000);       // 2 MB
  float* bdT  = (float*)(ws + 0x220000);      // 4 MB
  u16*   xb   = (u16*)  (ws + 0x620000);      // 32 MB
  u16*   wt   = (u16*)  (ws + 0x2620000);     // 32 MB (WdT, then reused for WuT)
  u16*   mid  = (u16*)  (ws + 0x4620000);     // 32 MB
  float* part = (float*)(ws + 0x4620000);     // 32 MB, aliases mid (dead before gemm1)

  cvt_kernel<<<dim3(8192), dim3(256), 0, stream>>>(x, xb);
  ln_kernel<<<dim3(16), dim3(256), 0, stream>>>(ada, gamma, beta, c);
  h_kernel<<<dim3(4, 16), dim3(256), 0, stream>>>(c, W1, bias1, h);
  w_part_kernel<<<dim3(32, WSPLIT), dim3(256), 0, stream>>>(h, W2, part);
  w_reduce_kernel<<<dim3(2048), dim3(256), 0, stream>>>(part, bias2, w);
  transpose_kernel<<<dim3(32, 32), dim3(256), 0, stream>>>(base_down, bdT);
  fold_down_kernel<<<dim3(512, 16), dim3(256), 0, stream>>>(bdT, w, wt);
  gemm_kernel<1><<<dim3(8, 8, 16), dim3(256), 0, stream>>>(xb, wt, (const u16*)nullptr, (void*)mid);
  fold_up_kernel<<<dim3(512, 16), dim3(256), 0, stream>>>(base_up, w, wt);
  gemm_kernel<2><<<dim3(8, 8, 16), dim3(256), 0, stream>>>(mid, wt, xb, (void*)out);
}

// Round 3
// 340.316 us; speedup vs baseline: 1.5937x; 1.3221x over previous
//
#include <hip/hip_runtime.h>
#include <math.h>

#define DD 1024
#define NB 16
#define WSPLIT 16
#define HSPLIT 32

typedef unsigned short u16;
typedef __attribute__((ext_vector_type(8))) short short8;
typedef __attribute__((ext_vector_type(4))) float f32x4;

__device__ __forceinline__ float gelu_f(float x) {
  return 0.5f * x * (1.0f + erff(x * 0.70710678118654752440f));
}
__device__ __forceinline__ u16 f2bf(float f) {
  union { float f; unsigned u; } v; v.f = f;
  return (u16)((v.u + 0x7FFFu + ((v.u >> 16) & 1u)) >> 16);
}
__device__ __forceinline__ float bf2f(u16 b) {
  union { unsigned u; float f; } v; v.u = ((unsigned)b) << 16;
  return v.f;
}
__device__ __forceinline__ void gload_lds16(const u16* g, u16* l) {
  __builtin_amdgcn_global_load_lds(
      (const __attribute__((address_space(1))) void*)g,
      (__attribute__((address_space(3))) void*)l, 16, 0, 0);
}

// ---------------- x (f32) -> bf16 ----------------
__launch_bounds__(256)
__global__ void cvt_kernel(const float* __restrict__ x, u16* __restrict__ xb) {
  size_t i = (size_t)blockIdx.x * 256 + threadIdx.x;   // each thread: 8 elements
  const float4* xf = (const float4*)x;
  float4 v0 = xf[i * 2], v1 = xf[i * 2 + 1];
  short8 o;
  o[0] = (short)f2bf(v0.x); o[1] = (short)f2bf(v0.y);
  o[2] = (short)f2bf(v0.z); o[3] = (short)f2bf(v0.w);
  o[4] = (short)f2bf(v1.x); o[5] = (short)f2bf(v1.y);
  o[6] = (short)f2bf(v1.z); o[7] = (short)f2bf(v1.w);
  *(short8*)(xb + i * 8) = o;
}

// ---------------- LayerNorm over ada_emb rows ----------------
__launch_bounds__(256)
__global__ void ln_kernel(const float* __restrict__ ada, const float* __restrict__ gamma,
                          const float* __restrict__ beta, float* __restrict__ c) {
  int b = blockIdx.x;
  int t = threadIdx.x;
  const float* row = ada + b * DD;
  float s = 0.f, s2 = 0.f;
  for (int i = t; i < DD; i += 256) { float v = row[i]; s += v; s2 += v * v; }
  for (int off = 32; off; off >>= 1) { s += __shfl_down(s, off); s2 += __shfl_down(s2, off); }
  __shared__ float rs[4], rs2[4];
  int wave = t >> 6, lane = t & 63;
  if (lane == 0) { rs[wave] = s; rs2[wave] = s2; }
  __syncthreads();
  if (t == 0) {
    float a = 0.f, a2 = 0.f;
    for (int w = 0; w < 4; w++) { a += rs[w]; a2 += rs2[w]; }
    rs[0] = a * (1.0f / DD); rs2[0] = a2 * (1.0f / DD);
  }
  __syncthreads();
  float mu = rs[0];
  float var = rs2[0] - mu * mu;
  float inv = rsqrtf(var + 1e-5f);
  for (int i = t; i < DD; i += 256)
    c[b * DD + i] = (row[i] - mu) * inv * gamma[i] + beta[i];
}

// ------- h partials: split-K over W1 (32 splits of 32) -------
// hpart[s][b][j] = c[b][k0..k0+32) . W1[k0..k0+32)[j]
__launch_bounds__(256)
__global__ void h_part_kernel(const float* __restrict__ c, const float* __restrict__ W1,
                              float* __restrict__ hpart) {
  int s = blockIdx.y;
  int j = blockIdx.x * 256 + threadIdx.x;
  int k0 = s * 32;
  __shared__ float cs[NB][32];                 // 2 KB
  for (int i = threadIdx.x; i < NB * 32; i += 256)
    cs[i >> 5][i & 31] = c[(size_t)(i >> 5) * DD + k0 + (i & 31)];
  __syncthreads();
  float acc[NB];
  #pragma unroll
  for (int b = 0; b < NB; b++) acc[b] = 0.f;
  #pragma unroll
  for (int al = 0; al < 32; al++) {
    float wv = W1[(size_t)(k0 + al) * DD + j];
    #pragma unroll
    for (int b = 0; b < NB; b++) acc[b] += cs[b][al] * wv;
  }
  #pragma unroll
  for (int b = 0; b < NB; b++)
    hpart[((size_t)s * NB + b) * DD + j] = acc[b];
}

// ------- h = gelu(sum_s hpart[s] + bias1) -------
__launch_bounds__(256)
__global__ void h_reduce_kernel(const float* __restrict__ hpart, const float* __restrict__ bias1,
                                float* __restrict__ h) {
  int idx = blockIdx.x * 256 + threadIdx.x;    // b*DD + j, grid 64
  int j = idx & (DD - 1);
  float acc = bias1[j];
  #pragma unroll
  for (int s = 0; s < HSPLIT; s++) acc += hpart[(size_t)s * NB * DD + idx];
  h[idx] = gelu_f(acc);
}

// ------- w partials: split-K over W2 (16 splits of 64), float4 columns -------
__launch_bounds__(256)
__global__ void w_part_kernel(const float* __restrict__ h, const float* __restrict__ W2,
                              float* __restrict__ part) {
  int s = blockIdx.y;                          // k-split
  int j4 = blockIdx.x * 256 + threadIdx.x;     // float4 column index, 0..8191
  int k0 = s * 64;
  int t = threadIdx.x;
  __shared__ float hl[NB][64];                 // 4 KB
  for (int i = t; i < NB * 64; i += 256) hl[i >> 6][i & 63] = h[(size_t)(i >> 6) * DD + k0 + (i & 63)];
  __syncthreads();
  float4 acc[NB];
  #pragma unroll
  for (int b = 0; b < NB; b++) acc[b] = float4{0.f, 0.f, 0.f, 0.f};
  const float4* W2v = (const float4*)W2;       // row stride 8192 float4
  #pragma unroll 4
  for (int al = 0; al < 64; al++) {
    float4 wv = W2v[(size_t)(k0 + al) * 8192 + j4];
    #pragma unroll
    for (int b = 0; b < NB; b++) {
      float hb = hl[b][al];
      acc[b].x += hb * wv.x; acc[b].y += hb * wv.y;
      acc[b].z += hb * wv.z; acc[b].w += hb * wv.w;
    }
  }
  float4* pv = (float4*)part;
  #pragma unroll
  for (int b = 0; b < NB; b++)
    pv[((size_t)s * NB + b) * 8192 + j4] = acc[b];
}

// ------- w = sum_s part[s] + bias2 -------
__launch_bounds__(256)
__global__ void w_reduce_kernel(const float* __restrict__ part, const float* __restrict__ bias2,
                                float* __restrict__ w) {
  int idx = blockIdx.x * 256 + threadIdx.x;    // b*32768 + j, grid 2048
  int j = idx & 32767;
  float acc = bias2[j];
  #pragma unroll
  for (int s = 0; s < WSPLIT; s++) acc += part[(size_t)s * NB * 32768 + idx];
  w[idx] = acc;
}

// ---------------- transpose base_down (f32 1024x1024) ----------------
__launch_bounds__(256)
__global__ void transpose_kernel(const float* __restrict__ in, float* __restrict__ out) {
  __shared__ float tile[32][33];
  int bx = blockIdx.x * 32, by = blockIdx.y * 32;
  int tx = threadIdx.x & 31, ty = threadIdx.x >> 5;   // 32 x 8
  for (int r = ty; r < 32; r += 8) tile[r][tx] = in[(size_t)(by + r) * DD + bx + tx];
  __syncthreads();
  for (int r = ty; r < 32; r += 8) out[(size_t)(bx + r) * DD + by + tx] = tile[tx][r];
}

// ---- fold WdT[b][l][d] = base_downT[l][d] + sum_r a2[d][r]*b2[l][r] (bf16) ----
__launch_bounds__(256)
__global__ void fold_down_kernel(const float* __restrict__ bdT, const float* __restrict__ w,
                                 u16* __restrict__ wt) {
  int b = blockIdx.y;
  const float* wb = w + (size_t)b * 32768;
  size_t base = (size_t)b << 20;
  int idx8 = blockIdx.x * 256 + threadIdx.x;
  int l = idx8 >> 7;
  int d0 = (idx8 & 127) << 3;
  float b2v[8];
  #pragma unroll
  for (int r = 0; r < 8; r++) b2v[r] = wb[24576 + l * 8 + r];
  short8 ov;
  #pragma unroll
  for (int jj = 0; jj < 8; jj++) {
    int d = d0 + jj;
    float acc = bdT[(size_t)l * DD + d];
    const float* a2 = wb + 16384 + d * 8;
    #pragma unroll
    for (int r = 0; r < 8; r++) acc += a2[r] * b2v[r];
    ov[jj] = (short)f2bf(acc);
  }
  *(short8*)(wt + base + (size_t)l * DD + d0) = ov;
}

// ---- fold WuT[b][k][l] = base_up[k][l] + sum_r a1[k][r]*b1[l][r] (bf16) ----
__launch_bounds__(256)
__global__ void fold_up_kernel(const float* __restrict__ bu, const float* __restrict__ w,
                               u16* __restrict__ wt) {
  int b = blockIdx.y;
  const float* wb = w + (size_t)b * 32768;
  size_t base = (size_t)b << 20;
  int idx8 = blockIdx.x * 256 + threadIdx.x;
  int k = idx8 >> 7;
  int l0 = (idx8 & 127) << 3;
  float a1v[8];
  #pragma unroll
  for (int r = 0; r < 8; r++) a1v[r] = wb[k * 8 + r];
  short8 ov;
  #pragma unroll
  for (int jj = 0; jj < 8; jj++) {
    int l = l0 + jj;
    float acc = bu[(size_t)k * DD + l];
    const float* b1 = wb + 8192 + l * 8;
    #pragma unroll
    for (int r = 0; r < 8; r++) acc += b1[r] * a1v[r];
    ov[jj] = (short)f2bf(acc);
  }
  *(short8*)(wt + base + (size_t)k * DD + l0) = ov;
}

// ------------- batched GEMM: C = A(bf16) @ BT(bf16)^T, 128x128 tile -------------
// global_load_lds(16B) staging, linear LDS + pre-swizzled SOURCE + swizzled ds_read.
// PHASE 1: C = gelu(A@B) -> bf16 mid.  PHASE 2: C = resid + A@B -> f32 out.
template<int PHASE>
__launch_bounds__(256)
__global__ void gemm_kernel(const u16* __restrict__ A, const u16* __restrict__ BT,
                            const u16* __restrict__ resid, void* __restrict__ Cout) {
  constexpr int BK = 64;
  __shared__ __align__(16) u16 As[128 * BK];
  __shared__ __align__(16) u16 Bs[128 * BK];
  int b = blockIdx.z;
  int tm = blockIdx.y, tn = blockIdx.x;
  const u16* Ab = A + ((size_t)b << 20) + (size_t)(tm * 128) * DD;
  const u16* Bb = BT + ((size_t)b << 20) + (size_t)(tn * 128) * DD;
  int t = threadIdx.x, lane = t & 63, g = lane >> 4, l15 = lane & 15;
  int wave = t >> 6, wm = wave >> 1, wn = wave & 1;

  int srow[4], se[4], woff[4];
  #pragma unroll
  for (int c = 0; c < 4; c++) {
    woff[c] = (wave * 4 + c) * 1024;           // byte offset of wave chunk
    int off = woff[c] + lane * 16;             // this lane's LDS byte slot
    int row = off >> 7;
    int c8 = (off >> 4) & 7;
    srow[c] = row;
    se[c] = (c8 ^ (row & 7)) << 3;             // element offset in global row
  }

  f32x4 acc[4][4] = {};

  for (int ks = 0; ks < DD; ks += BK) {
    #pragma unroll
    for (int c = 0; c < 4; c++) {
      gload_lds16(Ab + (size_t)srow[c] * DD + ks + se[c], (u16*)((char*)As + woff[c]));
      gload_lds16(Bb + (size_t)srow[c] * DD + ks + se[c], (u16*)((char*)Bs + woff[c]));
    }
    __syncthreads();
    #pragma unroll
    for (int kk = 0; kk < 2; kk++) {
      short8 af[4], bf[4];
      #pragma unroll
      for (int i = 0; i < 4; i++) {
        int row = wm * 64 + i * 16 + l15;
        int e = (kk * 32 + g * 8) ^ ((row & 7) << 3);
        af[i] = *(const short8*)(As + row * BK + e);
      }
      #pragma unroll
      for (int j = 0; j < 4; j++) {
        int row = wn * 64 + j * 16 + l15;
        int e = (kk * 32 + g * 8) ^ ((row & 7) << 3);
        bf[j] = *(const short8*)(Bs + row * BK + e);
      }
      #pragma unroll
      for (int i = 0; i < 4; i++)
        #pragma unroll
        for (int j = 0; j < 4; j++)
          acc[i][j] = __builtin_amdgcn_mfma_f32_16x16x32_bf16(af[i], bf[j], acc[i][j], 0, 0, 0);
    }
    __syncthreads();
  }

  int r0 = tm * 128 + wm * 64, c0 = tn * 128 + wn * 64;
  if (PHASE == 1) {
    u16* mid = (u16*)Cout + ((size_t)b << 20);
    #pragma unroll
    for (int i = 0; i < 4; i++)
      #pragma unroll
      for (int j = 0; j < 4; j++)
        #pragma unroll
        for (int r = 0; r < 4; r++) {
          int row = r0 + i * 16 + g * 4 + r;
          int col = c0 + j * 16 + l15;
          mid[(size_t)row * DD + col] = f2bf(gelu_f(acc[i][j][r]));
        }
  } else {
    float* out = (float*)Cout + ((size_t)b << 20);
    const u16* xb = resid + ((size_t)b << 20);
    #pragma unroll
    for (int i = 0; i < 4; i++)
      #pragma unroll
      for (int j = 0; j < 4; j++)
        #pragma unroll
        for (int r = 0; r < 4; r++) {
          int row = r0 + i * 16 + g * 4 + r;
          int col = c0 + j * 16 + l15;
          size_t idx = (size_t)row * DD + col;
          out[idx] = bf2f(xb[idx]) + acc[i][j][r];
        }
  }
}

extern "C" void kernel_launch(void* const* d_in, const int* in_sizes, int n_in,
                              void* d_out, int out_size, void* d_ws, size_t ws_size,
                              hipStream_t stream) {
  const float* x         = (const float*)d_in[0];
  const float* ada       = (const float*)d_in[1];
  const float* base_up   = (const float*)d_in[2];
  const float* base_down = (const float*)d_in[3];
  const float* gamma     = (const float*)d_in[4];
  const float* beta      = (const float*)d_in[5];
  const float* W1        = (const float*)d_in[6];
  const float* bias1     = (const float*)d_in[7];
  const float* W2        = (const float*)d_in[8];
  const float* bias2     = (const float*)d_in[9];
  float* out = (float*)d_out;
  char* ws = (char*)d_ws;

  float* c     = (float*)(ws);                 // 64 KB
  float* h     = (float*)(ws + 0x10000);       // 64 KB
  float* w     = (float*)(ws + 0x20000);       // 2 MB
  float* bdT   = (float*)(ws + 0x220000);      // 4 MB
  float* hpart = (float*)(ws + 0x220000);      // 2 MB, aliases bdT (dead until transpose)
  u16*   xb    = (u16*)  (ws + 0x620000);      // 32 MB
  u16*   wt    = (u16*)  (ws + 0x2620000);     // 32 MB (WdT, then reused for WuT)
  u16*   mid   = (u16*)  (ws + 0x4620000);     // 32 MB
  float* part  = (float*)(ws + 0x4620000);     // 32 MB, aliases mid (dead before gemm1)

  cvt_kernel<<<dim3(8192), dim3(256), 0, stream>>>(x, xb);
  ln_kernel<<<dim3(16), dim3(256), 0, stream>>>(ada, gamma, beta, c);
  h_part_kernel<<<dim3(4, HSPLIT), dim3(256), 0, stream>>>(c, W1, hpart);
  h_reduce_kernel<<<dim3(64), dim3(256), 0, stream>>>(hpart, bias1, h);
  w_part_kernel<<<dim3(32, WSPLIT), dim3(256), 0, stream>>>(h, W2, part);
  w_reduce_kernel<<<dim3(2048), dim3(256), 0, stream>>>(part, bias2, w);
  transpose_kernel<<<dim3(32, 32), dim3(256), 0, stream>>>(base_down, bdT);
  fold_down_kernel<<<dim3(512, 16), dim3(256), 0, stream>>>(bdT, w, wt);
  gemm_kernel<1><<<dim3(8, 8, 16), dim3(256), 0, stream>>>(xb, wt, (const u16*)nullptr, (void*)mid);
  fold_up_kernel<<<dim3(512, 16), dim3(256), 0, stream>>>(base_up, w, wt);
  gemm_kernel<2><<<dim3(8, 8, 16), dim3(256), 0, stream>>>(mid, wt, xb, (void*)out);
}

// Round 4
// 321.325 us; speedup vs baseline: 1.6879x; 1.0591x over previous
//
#include <hip/hip_runtime.h>
#include <math.h>

#define DD 1024
#define NB 16
#define WSPLIT 16
#define HSPLIT 32

typedef unsigned short u16;
typedef __attribute__((ext_vector_type(8))) short short8;
typedef __attribute__((ext_vector_type(4))) float f32x4;

__device__ __forceinline__ float gelu_f(float x) {
  return 0.5f * x * (1.0f + erff(x * 0.70710678118654752440f));
}
__device__ __forceinline__ u16 f2bf(float f) {
  union { float f; unsigned u; } v; v.f = f;
  return (u16)((v.u + 0x7FFFu + ((v.u >> 16) & 1u)) >> 16);
}
__device__ __forceinline__ float bf2f(u16 b) {
  union { unsigned u; float f; } v; v.u = ((unsigned)b) << 16;
  return v.f;
}
__device__ __forceinline__ void gload_lds16(const u16* g, u16* l) {
  __builtin_amdgcn_global_load_lds(
      (const __attribute__((address_space(1))) void*)g,
      (__attribute__((address_space(3))) void*)l, 16, 0, 0);
}

#define VMCNT8   asm volatile("s_waitcnt vmcnt(8)" ::: "memory")
#define VMCNT0   asm volatile("s_waitcnt vmcnt(0)" ::: "memory")
#define LGKMCNT0 asm volatile("s_waitcnt lgkmcnt(0)" ::: "memory")
#define BARRIER  asm volatile("s_barrier" ::: "memory")

// ---------------- x (f32) -> bf16 ----------------
__launch_bounds__(256)
__global__ void cvt_kernel(const float* __restrict__ x, u16* __restrict__ xb) {
  size_t i = (size_t)blockIdx.x * 256 + threadIdx.x;
  const float4* xf = (const float4*)x;
  float4 v0 = xf[i * 2], v1 = xf[i * 2 + 1];
  short8 o;
  o[0] = (short)f2bf(v0.x); o[1] = (short)f2bf(v0.y);
  o[2] = (short)f2bf(v0.z); o[3] = (short)f2bf(v0.w);
  o[4] = (short)f2bf(v1.x); o[5] = (short)f2bf(v1.y);
  o[6] = (short)f2bf(v1.z); o[7] = (short)f2bf(v1.w);
  *(short8*)(xb + i * 8) = o;
}

// ---------------- LayerNorm over ada_emb rows ----------------
__launch_bounds__(256)
__global__ void ln_kernel(const float* __restrict__ ada, const float* __restrict__ gamma,
                          const float* __restrict__ beta, float* __restrict__ c) {
  int b = blockIdx.x;
  int t = threadIdx.x;
  const float* row = ada + b * DD;
  float s = 0.f, s2 = 0.f;
  for (int i = t; i < DD; i += 256) { float v = row[i]; s += v; s2 += v * v; }
  for (int off = 32; off; off >>= 1) { s += __shfl_down(s, off); s2 += __shfl_down(s2, off); }
  __shared__ float rs[4], rs2[4];
  int wave = t >> 6, lane = t & 63;
  if (lane == 0) { rs[wave] = s; rs2[wave] = s2; }
  __syncthreads();
  if (t == 0) {
    float a = 0.f, a2 = 0.f;
    for (int w = 0; w < 4; w++) { a += rs[w]; a2 += rs2[w]; }
    rs[0] = a * (1.0f / DD); rs2[0] = a2 * (1.0f / DD);
  }
  __syncthreads();
  float mu = rs[0];
  float var = rs2[0] - mu * mu;
  float inv = rsqrtf(var + 1e-5f);
  for (int i = t; i < DD; i += 256)
    c[b * DD + i] = (row[i] - mu) * inv * gamma[i] + beta[i];
}

// ------- h partials: split-K over W1 (32 splits of 32) -------
__launch_bounds__(256)
__global__ void h_part_kernel(const float* __restrict__ c, const float* __restrict__ W1,
                              float* __restrict__ hpart) {
  int s = blockIdx.y;
  int j = blockIdx.x * 256 + threadIdx.x;
  int k0 = s * 32;
  __shared__ float cs[NB][32];
  for (int i = threadIdx.x; i < NB * 32; i += 256)
    cs[i >> 5][i & 31] = c[(size_t)(i >> 5) * DD + k0 + (i & 31)];
  __syncthreads();
  float acc[NB];
  #pragma unroll
  for (int b = 0; b < NB; b++) acc[b] = 0.f;
  #pragma unroll
  for (int al = 0; al < 32; al++) {
    float wv = W1[(size_t)(k0 + al) * DD + j];
    #pragma unroll
    for (int b = 0; b < NB; b++) acc[b] += cs[b][al] * wv;
  }
  #pragma unroll
  for (int b = 0; b < NB; b++)
    hpart[((size_t)s * NB + b) * DD + j] = acc[b];
}

// ------- h = gelu(sum_s hpart[s] + bias1) -------
__launch_bounds__(256)
__global__ void h_reduce_kernel(const float* __restrict__ hpart, const float* __restrict__ bias1,
                                float* __restrict__ h) {
  int idx = blockIdx.x * 256 + threadIdx.x;
  int j = idx & (DD - 1);
  float acc = bias1[j];
  #pragma unroll
  for (int s = 0; s < HSPLIT; s++) acc += hpart[(size_t)s * NB * DD + idx];
  h[idx] = gelu_f(acc);
}

// ------- w partials: split-K over W2 (16 splits of 64), float4 columns -------
__launch_bounds__(256)
__global__ void w_part_kernel(const float* __restrict__ h, const float* __restrict__ W2,
                              float* __restrict__ part) {
  int s = blockIdx.y;
  int j4 = blockIdx.x * 256 + threadIdx.x;
  int k0 = s * 64;
  int t = threadIdx.x;
  __shared__ float hl[NB][64];
  for (int i = t; i < NB * 64; i += 256) hl[i >> 6][i & 63] = h[(size_t)(i >> 6) * DD + k0 + (i & 63)];
  __syncthreads();
  float4 acc[NB];
  #pragma unroll
  for (int b = 0; b < NB; b++) acc[b] = float4{0.f, 0.f, 0.f, 0.f};
  const float4* W2v = (const float4*)W2;
  #pragma unroll 4
  for (int al = 0; al < 64; al++) {
    float4 wv = W2v[(size_t)(k0 + al) * 8192 + j4];
    #pragma unroll
    for (int b = 0; b < NB; b++) {
      float hb = hl[b][al];
      acc[b].x += hb * wv.x; acc[b].y += hb * wv.y;
      acc[b].z += hb * wv.z; acc[b].w += hb * wv.w;
    }
  }
  float4* pv = (float4*)part;
  #pragma unroll
  for (int b = 0; b < NB; b++)
    pv[((size_t)s * NB + b) * 8192 + j4] = acc[b];
}

// ------- w = sum_s part[s] + bias2 -------
__launch_bounds__(256)
__global__ void w_reduce_kernel(const float* __restrict__ part, const float* __restrict__ bias2,
                                float* __restrict__ w) {
  int idx = blockIdx.x * 256 + threadIdx.x;
  int j = idx & 32767;
  float acc = bias2[j];
  #pragma unroll
  for (int s = 0; s < WSPLIT; s++) acc += part[(size_t)s * NB * 32768 + idx];
  w[idx] = acc;
}

// ---------------- transpose base_down (f32 1024x1024) ----------------
__launch_bounds__(256)
__global__ void transpose_kernel(const float* __restrict__ in, float* __restrict__ out) {
  __shared__ float tile[32][33];
  int bx = blockIdx.x * 32, by = blockIdx.y * 32;
  int tx = threadIdx.x & 31, ty = threadIdx.x >> 5;
  for (int r = ty; r < 32; r += 8) tile[r][tx] = in[(size_t)(by + r) * DD + bx + tx];
  __syncthreads();
  for (int r = ty; r < 32; r += 8) out[(size_t)(bx + r) * DD + by + tx] = tile[tx][r];
}

// ---- fold WdT[b][l][d] = base_downT[l][d] + sum_r a2[d][r]*b2[l][r] (bf16) ----
__launch_bounds__(256)
__global__ void fold_down_kernel(const float* __restrict__ bdT, const float* __restrict__ w,
                                 u16* __restrict__ wt) {
  int b = blockIdx.y;
  const float* wb = w + (size_t)b * 32768;
  size_t base = (size_t)b << 20;
  int idx8 = blockIdx.x * 256 + threadIdx.x;
  int l = idx8 >> 7;
  int d0 = (idx8 & 127) << 3;
  float b2v[8];
  #pragma unroll
  for (int r = 0; r < 8; r++) b2v[r] = wb[24576 + l * 8 + r];
  short8 ov;
  #pragma unroll
  for (int jj = 0; jj < 8; jj++) {
    int d = d0 + jj;
    float acc = bdT[(size_t)l * DD + d];
    const float* a2 = wb + 16384 + d * 8;
    #pragma unroll
    for (int r = 0; r < 8; r++) acc += a2[r] * b2v[r];
    ov[jj] = (short)f2bf(acc);
  }
  *(short8*)(wt + base + (size_t)l * DD + d0) = ov;
}

// ---- fold WuT[b][k][l] = base_up[k][l] + sum_r a1[k][r]*b1[l][r] (bf16) ----
__launch_bounds__(256)
__global__ void fold_up_kernel(const float* __restrict__ bu, const float* __restrict__ w,
                               u16* __restrict__ wt) {
  int b = blockIdx.y;
  const float* wb = w + (size_t)b * 32768;
  size_t base = (size_t)b << 20;
  int idx8 = blockIdx.x * 256 + threadIdx.x;
  int k = idx8 >> 7;
  int l0 = (idx8 & 127) << 3;
  float a1v[8];
  #pragma unroll
  for (int r = 0; r < 8; r++) a1v[r] = wb[k * 8 + r];
  short8 ov;
  #pragma unroll
  for (int jj = 0; jj < 8; jj++) {
    int l = l0 + jj;
    float acc = bu[(size_t)k * DD + l];
    const float* b1 = wb + 8192 + l * 8;
    #pragma unroll
    for (int r = 0; r < 8; r++) acc += b1[r] * a1v[r];
    ov[jj] = (short)f2bf(acc);
  }
  *(short8*)(wt + base + (size_t)k * DD + l0) = ov;
}

// ------- batched GEMM 256x256 tile, 8 waves, counted-vmcnt double-buffer -------
// C = A(bf16) @ BT(bf16)^T.  PHASE 1: gelu -> bf16 mid.  PHASE 2: resid + acc -> f32.
#define STAGE(KT, BUF) do { int ks_ = (KT) * 64;                                   \
    _Pragma("unroll")                                                              \
    for (int c_ = 0; c_ < 4; c_++)                                                 \
      gload_lds16(Ab + (size_t)srow[c_] * DD + ks_ + se[c_], As[BUF] + ldsel[c_]); \
    _Pragma("unroll")                                                              \
    for (int c_ = 0; c_ < 4; c_++)                                                 \
      gload_lds16(Bb + (size_t)srow[c_] * DD + ks_ + se[c_], Bs[BUF] + ldsel[c_]); \
  } while (0)

template<int PHASE>
__launch_bounds__(512, 2)
__global__ void gemm256_kernel(const u16* __restrict__ A, const u16* __restrict__ BT,
                               const u16* __restrict__ resid, void* __restrict__ Cout) {
  constexpr int BK = 64;
  constexpr int NT = DD / BK;   // 16 K-tiles
  __shared__ __align__(16) u16 As[2][256 * BK];   // 64 KB
  __shared__ __align__(16) u16 Bs[2][256 * BK];   // 64 KB

  // XCD-aware decode: blockIdx round-robins XCDs; give each XCD 2 whole batches.
  int orig = blockIdx.x;
  int logical = (orig & 7) * 32 + (orig >> 3);
  int b = logical >> 4;
  int tile = logical & 15;
  int tm = tile >> 2, tn = tile & 3;

  const u16* Ab = A + ((size_t)b << 20) + (size_t)(tm * 256) * DD;
  const u16* Bb = BT + ((size_t)b << 20) + (size_t)(tn * 256) * DD;

  int t = threadIdx.x, lane = t & 63, g = lane >> 4, l15 = lane & 15;
  int wave = t >> 6;
  int wm = wave >> 2, wn = wave & 3;   // 2 x 4 wave grid; per-wave 128 x 64 output

  // staging map: 4 chunks x 16B per operand; linear LDS dest, pre-swizzled source
  int srow[4], se[4], ldsel[4];
  #pragma unroll
  for (int c = 0; c < 4; c++) {
    int chunk = c * 512 + t;            // 0..2047 -> 32 KB
    srow[c] = chunk >> 3;               // row 0..255
    se[c] = ((chunk & 7) ^ (srow[c] & 7)) << 3;
    ldsel[c] = chunk * 8;               // element offset
  }

  f32x4 acc[8][4] = {};

  STAGE(0, 0);
  STAGE(1, 1);

  int cur = 0;
  #pragma unroll 1
  for (int kt = 0; kt < NT; kt++) {
    if (kt < NT - 1) { VMCNT8; } else { VMCNT0; }
    BARRIER;
    {
      const u16* Ap = As[cur];
      const u16* Bp = Bs[cur];
      #pragma unroll
      for (int kk = 0; kk < 2; kk++) {
        short8 bfr[4];
        #pragma unroll
        for (int j = 0; j < 4; j++) {
          int r = wn * 64 + j * 16 + l15;
          int e = (kk * 32 + g * 8) ^ ((r & 7) << 3);
          bfr[j] = *(const short8*)(Bp + r * BK + e);
        }
        #pragma unroll
        for (int i = 0; i < 8; i++) {
          int r = wm * 128 + i * 16 + l15;
          int e = (kk * 32 + g * 8) ^ ((r & 7) << 3);
          short8 af = *(const short8*)(Ap + r * BK + e);
          #pragma unroll
          for (int j = 0; j < 4; j++)
            acc[i][j] = __builtin_amdgcn_mfma_f32_16x16x32_bf16(af, bfr[j], acc[i][j], 0, 0, 0);
        }
      }
    }
    LGKMCNT0;
    BARRIER;
    if (kt + 2 < NT) STAGE(kt + 2, cur);
    cur ^= 1;
  }

  int r0 = tm * 256 + wm * 128;
  int c0 = tn * 256 + wn * 64;
  if (PHASE == 1) {
    u16* mid = (u16*)Cout + ((size_t)b << 20);
    #pragma unroll
    for (int i = 0; i < 8; i++)
      #pragma unroll
      for (int j = 0; j < 4; j++)
        #pragma unroll
        for (int r = 0; r < 4; r++) {
          int row = r0 + i * 16 + g * 4 + r;
          int col = c0 + j * 16 + l15;
          mid[(size_t)row * DD + col] = f2bf(gelu_f(acc[i][j][r]));
        }
  } else {
    float* out = (float*)Cout + ((size_t)b << 20);
    const u16* xb = resid + ((size_t)b << 20);
    #pragma unroll
    for (int i = 0; i < 8; i++)
      #pragma unroll
      for (int j = 0; j < 4; j++)
        #pragma unroll
        for (int r = 0; r < 4; r++) {
          int row = r0 + i * 16 + g * 4 + r;
          int col = c0 + j * 16 + l15;
          size_t idx = (size_t)row * DD + col;
          out[idx] = bf2f(xb[idx]) + acc[i][j][r];
        }
  }
}

extern "C" void kernel_launch(void* const* d_in, const int* in_sizes, int n_in,
                              void* d_out, int out_size, void* d_ws, size_t ws_size,
                              hipStream_t stream) {
  const float* x         = (const float*)d_in[0];
  const float* ada       = (const float*)d_in[1];
  const float* base_up   = (const float*)d_in[2];
  const float* base_down = (const float*)d_in[3];
  const float* gamma     = (const float*)d_in[4];
  const float* beta      = (const float*)d_in[5];
  const float* W1        = (const float*)d_in[6];
  const float* bias1     = (const float*)d_in[7];
  const float* W2        = (const float*)d_in[8];
  const float* bias2     = (const float*)d_in[9];
  float* out = (float*)d_out;
  char* ws = (char*)d_ws;

  float* c     = (float*)(ws);                 // 64 KB
  float* h     = (float*)(ws + 0x10000);       // 64 KB
  float* w     = (float*)(ws + 0x20000);       // 2 MB
  float* bdT   = (float*)(ws + 0x220000);      // 4 MB
  float* hpart = (float*)(ws + 0x220000);      // 2 MB, aliases bdT (dead until transpose)
  u16*   xb    = (u16*)  (ws + 0x620000);      // 32 MB
  u16*   wt    = (u16*)  (ws + 0x2620000);     // 32 MB (WdT, then reused for WuT)
  u16*   mid   = (u16*)  (ws + 0x4620000);     // 32 MB
  float* part  = (float*)(ws + 0x4620000);     // 32 MB, aliases mid (dead before gemm1)

  cvt_kernel<<<dim3(8192), dim3(256), 0, stream>>>(x, xb);
  ln_kernel<<<dim3(16), dim3(256), 0, stream>>>(ada, gamma, beta, c);
  h_part_kernel<<<dim3(4, HSPLIT), dim3(256), 0, stream>>>(c, W1, hpart);
  h_reduce_kernel<<<dim3(64), dim3(256), 0, stream>>>(hpart, bias1, h);
  w_part_kernel<<<dim3(32, WSPLIT), dim3(256), 0, stream>>>(h, W2, part);
  w_reduce_kernel<<<dim3(2048), dim3(256), 0, stream>>>(part, bias2, w);
  transpose_kernel<<<dim3(32, 32), dim3(256), 0, stream>>>(base_down, bdT);
  fold_down_kernel<<<dim3(512, 16), dim3(256), 0, stream>>>(bdT, w, wt);
  gemm256_kernel<1><<<dim3(256), dim3(512), 0, stream>>>(xb, wt, (const u16*)nullptr, (void*)mid);
  fold_up_kernel<<<dim3(512, 16), dim3(256), 0, stream>>>(base_up, w, wt);
  gemm256_kernel<2><<<dim3(256), dim3(512), 0, stream>>>(mid, wt, xb, (void*)out);
}

// Round 5
// 317.479 us; speedup vs baseline: 1.7084x; 1.0121x over previous
//
#include <hip/hip_runtime.h>
#include <math.h>

#define DD 1024
#define NB 16
#define WSPLIT 16
#define HSPLIT 32

typedef unsigned short u16;
typedef __attribute__((ext_vector_type(8))) short short8;
typedef __attribute__((ext_vector_type(4))) float f32x4;

__device__ __forceinline__ float gelu_f(float x) {
  return 0.5f * x * (1.0f + erff(x * 0.70710678118654752440f));
}
__device__ __forceinline__ u16 f2bf(float f) {
  union { float f; unsigned u; } v; v.f = f;
  return (u16)((v.u + 0x7FFFu + ((v.u >> 16) & 1u)) >> 16);
}
__device__ __forceinline__ float bf2f(u16 b) {
  union { unsigned u; float f; } v; v.u = ((unsigned)b) << 16;
  return v.f;
}
__device__ __forceinline__ void gload_lds16(const u16* g, u16* l) {
  __builtin_amdgcn_global_load_lds(
      (const __attribute__((address_space(1))) void*)g,
      (__attribute__((address_space(3))) void*)l, 16, 0, 0);
}

#define VMCNT8   asm volatile("s_waitcnt vmcnt(8)" ::: "memory")
#define VMCNT0   asm volatile("s_waitcnt vmcnt(0)" ::: "memory")
#define BARRIER  asm volatile("s_barrier" ::: "memory")

// ---------------- x (f32) -> bf16 ----------------
__launch_bounds__(256)
__global__ void cvt_kernel(const float* __restrict__ x, u16* __restrict__ xb) {
  size_t i = (size_t)blockIdx.x * 256 + threadIdx.x;
  const float4* xf = (const float4*)x;
  float4 v0 = xf[i * 2], v1 = xf[i * 2 + 1];
  short8 o;
  o[0] = (short)f2bf(v0.x); o[1] = (short)f2bf(v0.y);
  o[2] = (short)f2bf(v0.z); o[3] = (short)f2bf(v0.w);
  o[4] = (short)f2bf(v1.x); o[5] = (short)f2bf(v1.y);
  o[6] = (short)f2bf(v1.z); o[7] = (short)f2bf(v1.w);
  *(short8*)(xb + i * 8) = o;
}

// ---------------- LayerNorm over ada_emb rows ----------------
__launch_bounds__(256)
__global__ void ln_kernel(const float* __restrict__ ada, const float* __restrict__ gamma,
                          const float* __restrict__ beta, float* __restrict__ c) {
  int b = blockIdx.x;
  int t = threadIdx.x;
  const float* row = ada + b * DD;
  float s = 0.f, s2 = 0.f;
  for (int i = t; i < DD; i += 256) { float v = row[i]; s += v; s2 += v * v; }
  for (int off = 32; off; off >>= 1) { s += __shfl_down(s, off); s2 += __shfl_down(s2, off); }
  __shared__ float rs[4], rs2[4];
  int wave = t >> 6, lane = t & 63;
  if (lane == 0) { rs[wave] = s; rs2[wave] = s2; }
  __syncthreads();
  if (t == 0) {
    float a = 0.f, a2 = 0.f;
    for (int w = 0; w < 4; w++) { a += rs[w]; a2 += rs2[w]; }
    rs[0] = a * (1.0f / DD); rs2[0] = a2 * (1.0f / DD);
  }
  __syncthreads();
  float mu = rs[0];
  float var = rs2[0] - mu * mu;
  float inv = rsqrtf(var + 1e-5f);
  for (int i = t; i < DD; i += 256)
    c[b * DD + i] = (row[i] - mu) * inv * gamma[i] + beta[i];
}

// ------- h partials: split-K over W1 (32 splits of 32) -------
__launch_bounds__(256)
__global__ void h_part_kernel(const float* __restrict__ c, const float* __restrict__ W1,
                              float* __restrict__ hpart) {
  int s = blockIdx.y;
  int j = blockIdx.x * 256 + threadIdx.x;
  int k0 = s * 32;
  __shared__ float cs[NB][32];
  for (int i = threadIdx.x; i < NB * 32; i += 256)
    cs[i >> 5][i & 31] = c[(size_t)(i >> 5) * DD + k0 + (i & 31)];
  __syncthreads();
  float acc[NB];
  #pragma unroll
  for (int b = 0; b < NB; b++) acc[b] = 0.f;
  #pragma unroll
  for (int al = 0; al < 32; al++) {
    float wv = W1[(size_t)(k0 + al) * DD + j];
    #pragma unroll
    for (int b = 0; b < NB; b++) acc[b] += cs[b][al] * wv;
  }
  #pragma unroll
  for (int b = 0; b < NB; b++)
    hpart[((size_t)s * NB + b) * DD + j] = acc[b];
}

// ------- h = gelu(sum_s hpart[s] + bias1) -------
__launch_bounds__(256)
__global__ void h_reduce_kernel(const float* __restrict__ hpart, const float* __restrict__ bias1,
                                float* __restrict__ h) {
  int idx = blockIdx.x * 256 + threadIdx.x;
  int j = idx & (DD - 1);
  float acc = bias1[j];
  #pragma unroll
  for (int s = 0; s < HSPLIT; s++) acc += hpart[(size_t)s * NB * DD + idx];
  h[idx] = gelu_f(acc);
}

// ------- w partials: split-K over W2 (16 splits of 64), float4 columns -------
__launch_bounds__(256)
__global__ void w_part_kernel(const float* __restrict__ h, const float* __restrict__ W2,
                              float* __restrict__ part) {
  int s = blockIdx.y;
  int j4 = blockIdx.x * 256 + threadIdx.x;
  int k0 = s * 64;
  int t = threadIdx.x;
  __shared__ float hl[NB][64];
  for (int i = t; i < NB * 64; i += 256) hl[i >> 6][i & 63] = h[(size_t)(i >> 6) * DD + k0 + (i & 63)];
  __syncthreads();
  float4 acc[NB];
  #pragma unroll
  for (int b = 0; b < NB; b++) acc[b] = float4{0.f, 0.f, 0.f, 0.f};
  const float4* W2v = (const float4*)W2;
  #pragma unroll 4
  for (int al = 0; al < 64; al++) {
    float4 wv = W2v[(size_t)(k0 + al) * 8192 + j4];
    #pragma unroll
    for (int b = 0; b < NB; b++) {
      float hb = hl[b][al];
      acc[b].x += hb * wv.x; acc[b].y += hb * wv.y;
      acc[b].z += hb * wv.z; acc[b].w += hb * wv.w;
    }
  }
  float4* pv = (float4*)part;
  #pragma unroll
  for (int b = 0; b < NB; b++)
    pv[((size_t)s * NB + b) * 8192 + j4] = acc[b];
}

// ------- w = sum_s part[s] + bias2 -------
__launch_bounds__(256)
__global__ void w_reduce_kernel(const float* __restrict__ part, const float* __restrict__ bias2,
                                float* __restrict__ w) {
  int idx = blockIdx.x * 256 + threadIdx.x;
  int j = idx & 32767;
  float acc = bias2[j];
  #pragma unroll
  for (int s = 0; s < WSPLIT; s++) acc += part[(size_t)s * NB * 32768 + idx];
  w[idx] = acc;
}

// ---------------- transpose base_down (f32 1024x1024) ----------------
__launch_bounds__(256)
__global__ void transpose_kernel(const float* __restrict__ in, float* __restrict__ out) {
  __shared__ float tile[32][33];
  int bx = blockIdx.x * 32, by = blockIdx.y * 32;
  int tx = threadIdx.x & 31, ty = threadIdx.x >> 5;
  for (int r = ty; r < 32; r += 8) tile[r][tx] = in[(size_t)(by + r) * DD + bx + tx];
  __syncthreads();
  for (int r = ty; r < 32; r += 8) out[(size_t)(bx + r) * DD + by + tx] = tile[tx][r];
}

// ---- fold WdT[b][l][d] = base_downT[l][d] + sum_r a2[d][r]*b2[l][r] (bf16) ----
__launch_bounds__(256)
__global__ void fold_down_kernel(const float* __restrict__ bdT, const float* __restrict__ w,
                                 u16* __restrict__ wt) {
  int b = blockIdx.y;
  const float* wb = w + (size_t)b * 32768;
  size_t base = (size_t)b << 20;
  int idx8 = blockIdx.x * 256 + threadIdx.x;
  int l = idx8 >> 7;
  int d0 = (idx8 & 127) << 3;
  float b2v[8];
  #pragma unroll
  for (int r = 0; r < 8; r++) b2v[r] = wb[24576 + l * 8 + r];
  short8 ov;
  #pragma unroll
  for (int jj = 0; jj < 8; jj++) {
    int d = d0 + jj;
    float acc = bdT[(size_t)l * DD + d];
    const float* a2 = wb + 16384 + d * 8;
    #pragma unroll
    for (int r = 0; r < 8; r++) acc += a2[r] * b2v[r];
    ov[jj] = (short)f2bf(acc);
  }
  *(short8*)(wt + base + (size_t)l * DD + d0) = ov;
}

// ---- fold WuT[b][k][l] = base_up[k][l] + sum_r a1[k][r]*b1[l][r] (bf16) ----
__launch_bounds__(256)
__global__ void fold_up_kernel(const float* __restrict__ bu, const float* __restrict__ w,
                               u16* __restrict__ wt) {
  int b = blockIdx.y;
  const float* wb = w + (size_t)b * 32768;
  size_t base = (size_t)b << 20;
  int idx8 = blockIdx.x * 256 + threadIdx.x;
  int k = idx8 >> 7;
  int l0 = (idx8 & 127) << 3;
  float a1v[8];
  #pragma unroll
  for (int r = 0; r < 8; r++) a1v[r] = wb[k * 8 + r];
  short8 ov;
  #pragma unroll
  for (int jj = 0; jj < 8; jj++) {
    int l = l0 + jj;
    float acc = bu[(size_t)k * DD + l];
    const float* b1 = wb + 8192 + l * 8;
    #pragma unroll
    for (int r = 0; r < 8; r++) acc += b1[r] * a1v[r];
    ov[jj] = (short)f2bf(acc);
  }
  *(short8*)(wt + base + (size_t)k * DD + l0) = ov;
}

// ------- batched GEMM 256x256 tile, 8 waves, 4-phase quadrant schedule -------
// C = A(bf16) @ BT(bf16)^T.  PHASE 1: gelu -> bf16 mid.  PHASE 2: resid + acc -> f32.
#define STAGE(KT, BUF) do { int ks_ = (KT) * 64;                                   \
    _Pragma("unroll")                                                              \
    for (int c_ = 0; c_ < 4; c_++)                                                 \
      gload_lds16(Ab + (size_t)srow[c_] * DD + ks_ + se[c_], As[BUF] + ldsel[c_]); \
    _Pragma("unroll")                                                              \
    for (int c_ = 0; c_ < 4; c_++)                                                 \
      gload_lds16(Bb + (size_t)srow[c_] * DD + ks_ + se[c_], Bs[BUF] + ldsel[c_]); \
  } while (0)

template<int PHASE>
__launch_bounds__(512, 2)
__global__ void gemm256_kernel(const u16* __restrict__ A, const u16* __restrict__ BT,
                               const u16* __restrict__ resid, void* __restrict__ Cout) {
  constexpr int BK = 64;
  constexpr int NT = DD / BK;   // 16 K-tiles
  __shared__ __align__(16) u16 As[2][256 * BK];   // 64 KB
  __shared__ __align__(16) u16 Bs[2][256 * BK];   // 64 KB

  // XCD-aware decode: each XCD owns 2 whole batches (L2-resident panels).
  int orig = blockIdx.x;
  int logical = (orig & 7) * 32 + (orig >> 3);
  int b = logical >> 4;
  int tile = logical & 15;
  int tm = tile >> 2, tn = tile & 3;

  const u16* Ab = A + ((size_t)b << 20) + (size_t)(tm * 256) * DD;
  const u16* Bb = BT + ((size_t)b << 20) + (size_t)(tn * 256) * DD;

  int t = threadIdx.x, lane = t & 63, g = lane >> 4, l15 = lane & 15;
  int wave = t >> 6;
  int wm = wave >> 2, wn = wave & 3;   // 2 x 4 wave grid; per-wave 128 x 64 output

  // staging map: linear LDS dest, pre-swizzled source (involution cancels on read)
  int srow[4], se[4], ldsel[4];
  #pragma unroll
  for (int c = 0; c < 4; c++) {
    int chunk = c * 512 + t;            // 0..2047 -> 32 KB
    srow[c] = chunk >> 3;               // row 0..255
    se[c] = ((chunk & 7) ^ (srow[c] & 7)) << 3;
    ldsel[c] = chunk * 8;               // element offset
  }

  f32x4 acc[8][4] = {};

  STAGE(0, 0);
  STAGE(1, 1);

  int cur = 0;
  #pragma unroll 1
  for (int kt = 0; kt < NT; kt++) {
    if (kt < NT - 1) { VMCNT8; } else { VMCNT0; }
    BARRIER;
    const u16* Ap = As[cur];
    const u16* Bp = Bs[cur];

    short8 afr[2][4], bf0[2][2], bf1[2][2];

    // ---- ph0: read A-half0 (8) + B-half0 (4); MFMA Q00 ----
    #pragma unroll
    for (int kk = 0; kk < 2; kk++) {
      #pragma unroll
      for (int i = 0; i < 4; i++) {
        int r = wm * 128 + i * 16 + l15;
        int e = (kk * 32 + g * 8) ^ ((r & 7) << 3);
        afr[kk][i] = *(const short8*)(Ap + r * BK + e);
      }
      #pragma unroll
      for (int j = 0; j < 2; j++) {
        int r = wn * 64 + j * 16 + l15;
        int e = (kk * 32 + g * 8) ^ ((r & 7) << 3);
        bf0[kk][j] = *(const short8*)(Bp + r * BK + e);
      }
    }
    __builtin_amdgcn_s_setprio(1);
    #pragma unroll
    for (int kk = 0; kk < 2; kk++)
      #pragma unroll
      for (int i = 0; i < 4; i++)
        #pragma unroll
        for (int j = 0; j < 2; j++)
          acc[i][j] = __builtin_amdgcn_mfma_f32_16x16x32_bf16(afr[kk][i], bf0[kk][j], acc[i][j], 0, 0, 0);
    __builtin_amdgcn_s_setprio(0);
    BARRIER;

    // ---- ph1: read B-half1 (4); MFMA Q01 (A0 x B1) ----
    #pragma unroll
    for (int kk = 0; kk < 2; kk++)
      #pragma unroll
      for (int j = 0; j < 2; j++) {
        int r = wn * 64 + (j + 2) * 16 + l15;
        int e = (kk * 32 + g * 8) ^ ((r & 7) << 3);
        bf1[kk][j] = *(const short8*)(Bp + r * BK + e);
      }
    __builtin_amdgcn_s_setprio(1);
    #pragma unroll
    for (int kk = 0; kk < 2; kk++)
      #pragma unroll
      for (int i = 0; i < 4; i++)
        #pragma unroll
        for (int j = 0; j < 2; j++)
          acc[i][j + 2] = __builtin_amdgcn_mfma_f32_16x16x32_bf16(afr[kk][i], bf1[kk][j], acc[i][j + 2], 0, 0, 0);
    __builtin_amdgcn_s_setprio(0);
    BARRIER;

    // ---- ph2: read A-half1 (8, LAST reads of this buffer); MFMA Q11 (A1 x B1) ----
    #pragma unroll
    for (int kk = 0; kk < 2; kk++)
      #pragma unroll
      for (int i = 0; i < 4; i++) {
        int r = wm * 128 + (i + 4) * 16 + l15;
        int e = (kk * 32 + g * 8) ^ ((r & 7) << 3);
        afr[kk][i] = *(const short8*)(Ap + r * BK + e);
      }
    __builtin_amdgcn_s_setprio(1);
    #pragma unroll
    for (int kk = 0; kk < 2; kk++)
      #pragma unroll
      for (int i = 0; i < 4; i++)
        #pragma unroll
        for (int j = 0; j < 2; j++)
          acc[i + 4][j + 2] = __builtin_amdgcn_mfma_f32_16x16x32_bf16(afr[kk][i], bf1[kk][j], acc[i + 4][j + 2], 0, 0, 0);
    __builtin_amdgcn_s_setprio(0);
    BARRIER;
    // all waves past their last LDS read of buf[cur] -> free to overwrite

    // ---- ph3: stage kt+2 into freed buf[cur]; MFMA Q10 (A1 x B0, regs only) ----
    if (kt + 2 < NT) STAGE(kt + 2, cur);
    __builtin_amdgcn_s_setprio(1);
    #pragma unroll
    for (int kk = 0; kk < 2; kk++)
      #pragma unroll
      for (int i = 0; i < 4; i++)
        #pragma unroll
        for (int j = 0; j < 2; j++)
          acc[i + 4][j] = __builtin_amdgcn_mfma_f32_16x16x32_bf16(afr[kk][i], bf0[kk][j], acc[i + 4][j], 0, 0, 0);
    __builtin_amdgcn_s_setprio(0);

    cur ^= 1;
  }

  int r0 = tm * 256 + wm * 128;
  int c0 = tn * 256 + wn * 64;
  if (PHASE == 1) {
    u16* mid = (u16*)Cout + ((size_t)b << 20);
    #pragma unroll
    for (int i = 0; i < 8; i++)
      #pragma unroll
      for (int j = 0; j < 4; j++)
        #pragma unroll
        for (int r = 0; r < 4; r++) {
          int row = r0 + i * 16 + g * 4 + r;
          int col = c0 + j * 16 + l15;
          mid[(size_t)row * DD + col] = f2bf(gelu_f(acc[i][j][r]));
        }
  } else {
    float* out = (float*)Cout + ((size_t)b << 20);
    const u16* xb = resid + ((size_t)b << 20);
    #pragma unroll
    for (int i = 0; i < 8; i++)
      #pragma unroll
      for (int j = 0; j < 4; j++)
        #pragma unroll
        for (int r = 0; r < 4; r++) {
          int row = r0 + i * 16 + g * 4 + r;
          int col = c0 + j * 16 + l15;
          size_t idx = (size_t)row * DD + col;
          out[idx] = bf2f(xb[idx]) + acc[i][j][r];
        }
  }
}

extern "C" void kernel_launch(void* const* d_in, const int* in_sizes, int n_in,
                              void* d_out, int out_size, void* d_ws, size_t ws_size,
                              hipStream_t stream) {
  const float* x         = (const float*)d_in[0];
  const float* ada       = (const float*)d_in[1];
  const float* base_up   = (const float*)d_in[2];
  const float* base_down = (const float*)d_in[3];
  const float* gamma     = (const float*)d_in[4];
  const float* beta      = (const float*)d_in[5];
  const float* W1        = (const float*)d_in[6];
  const float* bias1     = (const float*)d_in[7];
  const float* W2        = (const float*)d_in[8];
  const float* bias2     = (const float*)d_in[9];
  float* out = (float*)d_out;
  char* ws = (char*)d_ws;

  float* c     = (float*)(ws);                 // 64 KB
  float* h     = (float*)(ws + 0x10000);       // 64 KB
  float* w     = (float*)(ws + 0x20000);       // 2 MB
  float* bdT   = (float*)(ws + 0x220000);      // 4 MB
  float* hpart = (float*)(ws + 0x220000);      // 2 MB, aliases bdT (dead until transpose)
  u16*   xb    = (u16*)  (ws + 0x620000);      // 32 MB
  u16*   wt    = (u16*)  (ws + 0x2620000);     // 32 MB (WdT, then reused for WuT)
  u16*   mid   = (u16*)  (ws + 0x4620000);     // 32 MB
  float* part  = (float*)(ws + 0x4620000);     // 32 MB, aliases mid (dead before gemm1)

  cvt_kernel<<<dim3(8192), dim3(256), 0, stream>>>(x, xb);
  ln_kernel<<<dim3(16), dim3(256), 0, stream>>>(ada, gamma, beta, c);
  h_part_kernel<<<dim3(4, HSPLIT), dim3(256), 0, stream>>>(c, W1, hpart);
  h_reduce_kernel<<<dim3(64), dim3(256), 0, stream>>>(hpart, bias1, h);
  w_part_kernel<<<dim3(32, WSPLIT), dim3(256), 0, stream>>>(h, W2, part);
  w_reduce_kernel<<<dim3(2048), dim3(256), 0, stream>>>(part, bias2, w);
  transpose_kernel<<<dim3(32, 32), dim3(256), 0, stream>>>(base_down, bdT);
  fold_down_kernel<<<dim3(512, 16), dim3(256), 0, stream>>>(bdT, w, wt);
  gemm256_kernel<1><<<dim3(256), dim3(512), 0, stream>>>(xb, wt, (const u16*)nullptr, (void*)mid);
  fold_up_kernel<<<dim3(512, 16), dim3(256), 0, stream>>>(base_up, w, wt);
  gemm256_kernel<2><<<dim3(256), dim3(512), 0, stream>>>(mid, wt, xb, (void*)out);
}

// Round 6
// 312.038 us; speedup vs baseline: 1.7381x; 1.0174x over previous
//
#include <hip/hip_runtime.h>
#include <math.h>

#define DD 1024
#define NB 16
#define WSPLIT 16
#define HSPLIT 32

typedef unsigned short u16;
typedef __attribute__((ext_vector_type(8))) short short8;
typedef __attribute__((ext_vector_type(4))) float f32x4;

__device__ __forceinline__ float gelu_f(float x) {
  return 0.5f * x * (1.0f + erff(x * 0.70710678118654752440f));
}
__device__ __forceinline__ u16 f2bf(float f) {
  union { float f; unsigned u; } v; v.f = f;
  return (u16)((v.u + 0x7FFFu + ((v.u >> 16) & 1u)) >> 16);
}
__device__ __forceinline__ float bf2f(u16 b) {
  union { unsigned u; float f; } v; v.u = ((unsigned)b) << 16;
  return v.f;
}
__device__ __forceinline__ void gload_lds16(const u16* g, u16* l) {
  __builtin_amdgcn_global_load_lds(
      (const __attribute__((address_space(1))) void*)g,
      (__attribute__((address_space(3))) void*)l, 16, 0, 0);
}

#define VMCNT8   asm volatile("s_waitcnt vmcnt(8)" ::: "memory")
#define VMCNT0   asm volatile("s_waitcnt vmcnt(0)" ::: "memory")
#define BARRIER  asm volatile("s_barrier" ::: "memory")

// ---- fused prep: [0,8192) cvt x->bf16 | [8192,8208) LN | [8208,9232) transpose ----
__launch_bounds__(256)
__global__ void prep_kernel(const float* __restrict__ x, u16* __restrict__ xb,
                            const float* __restrict__ ada, const float* __restrict__ gamma,
                            const float* __restrict__ beta, float* __restrict__ c,
                            const float* __restrict__ bdn, float* __restrict__ bdT) {
  __shared__ float smem[1056];
  int bid = blockIdx.x;
  int t = threadIdx.x;
  if (bid < 8192) {
    size_t i = (size_t)bid * 256 + t;
    const float4* xf = (const float4*)x;
    float4 v0 = xf[i * 2], v1 = xf[i * 2 + 1];
    short8 o;
    o[0] = (short)f2bf(v0.x); o[1] = (short)f2bf(v0.y);
    o[2] = (short)f2bf(v0.z); o[3] = (short)f2bf(v0.w);
    o[4] = (short)f2bf(v1.x); o[5] = (short)f2bf(v1.y);
    o[6] = (short)f2bf(v1.z); o[7] = (short)f2bf(v1.w);
    *(short8*)(xb + i * 8) = o;
  } else if (bid < 8208) {
    int b = bid - 8192;
    const float* row = ada + b * DD;
    float s = 0.f, s2 = 0.f;
    for (int i = t; i < DD; i += 256) { float v = row[i]; s += v; s2 += v * v; }
    for (int off = 32; off; off >>= 1) { s += __shfl_down(s, off); s2 += __shfl_down(s2, off); }
    float* rs = smem; float* rs2 = smem + 4;
    int wave = t >> 6, lane = t & 63;
    if (lane == 0) { rs[wave] = s; rs2[wave] = s2; }
    __syncthreads();
    if (t == 0) {
      float a = 0.f, a2 = 0.f;
      for (int w = 0; w < 4; w++) { a += rs[w]; a2 += rs2[w]; }
      rs[0] = a * (1.0f / DD); rs2[0] = a2 * (1.0f / DD);
    }
    __syncthreads();
    float mu = rs[0];
    float var = rs2[0] - mu * mu;
    float inv = rsqrtf(var + 1e-5f);
    for (int i = t; i < DD; i += 256)
      c[b * DD + i] = (row[i] - mu) * inv * gamma[i] + beta[i];
  } else {
    int t2 = bid - 8208;
    int bx = (t2 & 31) * 32, by = (t2 >> 5) * 32;
    float (*tile)[33] = (float(*)[33])smem;
    int tx = t & 31, ty = t >> 5;   // 32 x 8
    for (int r = ty; r < 32; r += 8) tile[r][tx] = bdn[(size_t)(by + r) * DD + bx + tx];
    __syncthreads();
    for (int r = ty; r < 32; r += 8) bdT[(size_t)(bx + r) * DD + by + tx] = tile[tx][r];
  }
}

// ------- h partials: split-K over W1 (32 splits of 32) -------
__launch_bounds__(256)
__global__ void h_part_kernel(const float* __restrict__ c, const float* __restrict__ W1,
                              float* __restrict__ hpart) {
  int s = blockIdx.y;
  int j = blockIdx.x * 256 + threadIdx.x;
  int k0 = s * 32;
  __shared__ float cs[NB][32];
  for (int i = threadIdx.x; i < NB * 32; i += 256)
    cs[i >> 5][i & 31] = c[(size_t)(i >> 5) * DD + k0 + (i & 31)];
  __syncthreads();
  float acc[NB];
  #pragma unroll
  for (int b = 0; b < NB; b++) acc[b] = 0.f;
  #pragma unroll
  for (int al = 0; al < 32; al++) {
    float wv = W1[(size_t)(k0 + al) * DD + j];
    #pragma unroll
    for (int b = 0; b < NB; b++) acc[b] += cs[b][al] * wv;
  }
  #pragma unroll
  for (int b = 0; b < NB; b++)
    hpart[((size_t)s * NB + b) * DD + j] = acc[b];
}

// ------- h = gelu(sum_s hpart[s] + bias1) -------
__launch_bounds__(256)
__global__ void h_reduce_kernel(const float* __restrict__ hpart, const float* __restrict__ bias1,
                                float* __restrict__ h) {
  int idx = blockIdx.x * 256 + threadIdx.x;
  int j = idx & (DD - 1);
  float acc = bias1[j];
  #pragma unroll
  for (int s = 0; s < HSPLIT; s++) acc += hpart[(size_t)s * NB * DD + idx];
  h[idx] = gelu_f(acc);
}

// ------- w partials: split-K over W2 (16 splits of 64), float4 columns -------
__launch_bounds__(256)
__global__ void w_part_kernel(const float* __restrict__ h, const float* __restrict__ W2,
                              float* __restrict__ part) {
  int s = blockIdx.y;
  int j4 = blockIdx.x * 256 + threadIdx.x;
  int k0 = s * 64;
  int t = threadIdx.x;
  __shared__ float hl[NB][64];
  for (int i = t; i < NB * 64; i += 256) hl[i >> 6][i & 63] = h[(size_t)(i >> 6) * DD + k0 + (i & 63)];
  __syncthreads();
  float4 acc[NB];
  #pragma unroll
  for (int b = 0; b < NB; b++) acc[b] = float4{0.f, 0.f, 0.f, 0.f};
  const float4* W2v = (const float4*)W2;
  #pragma unroll 4
  for (int al = 0; al < 64; al++) {
    float4 wv = W2v[(size_t)(k0 + al) * 8192 + j4];
    #pragma unroll
    for (int b = 0; b < NB; b++) {
      float hb = hl[b][al];
      acc[b].x += hb * wv.x; acc[b].y += hb * wv.y;
      acc[b].z += hb * wv.z; acc[b].w += hb * wv.w;
    }
  }
  float4* pv = (float4*)part;
  #pragma unroll
  for (int b = 0; b < NB; b++)
    pv[((size_t)s * NB + b) * 8192 + j4] = acc[b];
}

// ------- w = sum_s part[s] + bias2 -------
__launch_bounds__(256)
__global__ void w_reduce_kernel(const float* __restrict__ part, const float* __restrict__ bias2,
                                float* __restrict__ w) {
  int idx = blockIdx.x * 256 + threadIdx.x;
  int j = idx & 32767;
  float acc = bias2[j];
  #pragma unroll
  for (int s = 0; s < WSPLIT; s++) acc += part[(size_t)s * NB * 32768 + idx];
  w[idx] = acc;
}

// ---- fused fold: z=0 -> WdT[b][l][d]=bdT[l][d]+a2[d].b2[l]; z=1 -> WuT[b][k][l]=bu[k][l]+b1[l].a1[k] ----
__launch_bounds__(256)
__global__ void fold_kernel(const float* __restrict__ bdT, const float* __restrict__ bu,
                            const float* __restrict__ w, u16* __restrict__ wtd,
                            u16* __restrict__ wtu) {
  int b = blockIdx.y;
  int up = blockIdx.z;
  const float* wb = w + (size_t)b * 32768;
  size_t base = (size_t)b << 20;
  int idx8 = blockIdx.x * 256 + threadIdx.x;
  int l = idx8 >> 7;
  int d0 = (idx8 & 127) << 3;
  const float* rowv = wb + (up ? 0 : 24576) + l * 8;
  const float* colbase = wb + (up ? 8192 : 16384);
  const float* bm = (up ? bu : bdT) + (size_t)l * DD;
  u16* outp = (up ? wtu : wtd) + base + (size_t)l * DD + d0;
  float rv[8];
  #pragma unroll
  for (int r = 0; r < 8; r++) rv[r] = rowv[r];
  short8 ov;
  #pragma unroll
  for (int jj = 0; jj < 8; jj++) {
    int d = d0 + jj;
    float acc = bm[d];
    const float* cv = colbase + d * 8;
    #pragma unroll
    for (int r = 0; r < 8; r++) acc += cv[r] * rv[r];
    ov[jj] = (short)f2bf(acc);
  }
  *(short8*)outp = ov;
}

// ------- batched GEMM 256x256 tile, 8 waves, m201-style phased schedule -------
// C = A(bf16) @ BT(bf16)^T.  PHASE 1: gelu -> bf16 mid.  PHASE 2: resid + acc -> f32.
#define STAGE_A(KT, BUF) do { int ks_ = (KT) * 64;                                   \
    _Pragma("unroll")                                                                \
    for (int c_ = 0; c_ < 4; c_++)                                                   \
      gload_lds16(Ab + (size_t)srow[c_] * DD + ks_ + se[c_], As[BUF] + ldsel[c_]);   \
  } while (0)
#define STAGE_B(KT, BUF) do { int ks_ = (KT) * 64;                                   \
    _Pragma("unroll")                                                                \
    for (int c_ = 0; c_ < 4; c_++)                                                   \
      gload_lds16(Bb + (size_t)srow[c_] * DD + ks_ + se[c_], Bs[BUF] + ldsel[c_]);   \
  } while (0)

template<int PHASE>
__launch_bounds__(512, 2)
__global__ void gemm256_kernel(const u16* __restrict__ A, const u16* __restrict__ BT,
                               const u16* __restrict__ resid, void* __restrict__ Cout) {
  constexpr int BK = 64;
  constexpr int NT = DD / BK;   // 16 K-tiles
  __shared__ __align__(16) u16 As[2][256 * BK];   // 64 KB
  __shared__ __align__(16) u16 Bs[2][256 * BK];   // 64 KB

  // XCD-aware decode: each XCD owns 2 whole batches (L2-resident panels).
  int orig = blockIdx.x;
  int logical = (orig & 7) * 32 + (orig >> 3);
  int b = logical >> 4;
  int tile = logical & 15;
  int tm = tile >> 2, tn = tile & 3;

  const u16* Ab = A + ((size_t)b << 20) + (size_t)(tm * 256) * DD;
  const u16* Bb = BT + ((size_t)b << 20) + (size_t)(tn * 256) * DD;

  int t = threadIdx.x, lane = t & 63, g = lane >> 4, l15 = lane & 15;
  int wave = t >> 6;
  int wm = wave >> 2, wn = wave & 3;   // 2 x 4 wave grid; per-wave 128 x 64 output

  // staging map: linear LDS dest, pre-swizzled source (involution cancels on read)
  int srow[4], se[4], ldsel[4];
  #pragma unroll
  for (int c = 0; c < 4; c++) {
    int chunk = c * 512 + t;            // 0..2047 -> 32 KB
    srow[c] = chunk >> 3;               // row 0..255
    se[c] = ((chunk & 7) ^ (srow[c] & 7)) << 3;
    ldsel[c] = chunk * 8;               // element offset
  }

  f32x4 acc[8][4] = {};

  STAGE_A(0, 0); STAGE_B(0, 0);
  STAGE_A(1, 1); STAGE_B(1, 1);
  VMCNT8;   // tile 0 resident
  BARRIER;

  int cur = 0;
  #pragma unroll 1
  for (int kt = 0; kt < NT; kt++) {
    const u16* Ap = As[cur];
    const u16* Bp = Bs[cur];
    short8 afr[2][4], bf0[2][2], bf1[2][2];

    // ---- ph0: read A-lo (8) + B-lo (4); Q00 ----
    #pragma unroll
    for (int kk = 0; kk < 2; kk++) {
      #pragma unroll
      for (int i = 0; i < 4; i++) {
        int r = wm * 128 + i * 16 + l15;
        int e = (kk * 32 + g * 8) ^ ((r & 7) << 3);
        afr[kk][i] = *(const short8*)(Ap + r * BK + e);
      }
      #pragma unroll
      for (int j = 0; j < 2; j++) {
        int r = wn * 64 + j * 16 + l15;
        int e = (kk * 32 + g * 8) ^ ((r & 7) << 3);
        bf0[kk][j] = *(const short8*)(Bp + r * BK + e);
      }
    }
    BARRIER;
    __builtin_amdgcn_s_setprio(1);
    #pragma unroll
    for (int kk = 0; kk < 2; kk++)
      #pragma unroll
      for (int i = 0; i < 4; i++)
        #pragma unroll
        for (int j = 0; j < 2; j++)
          acc[i][j] = __builtin_amdgcn_mfma_f32_16x16x32_bf16(afr[kk][i], bf0[kk][j], acc[i][j], 0, 0, 0);
    __builtin_amdgcn_s_setprio(0);
    BARRIER;

    // ---- ph1: read B-hi (4); Q01 ----
    #pragma unroll
    for (int kk = 0; kk < 2; kk++)
      #pragma unroll
      for (int j = 0; j < 2; j++) {
        int r = wn * 64 + (j + 2) * 16 + l15;
        int e = (kk * 32 + g * 8) ^ ((r & 7) << 3);
        bf1[kk][j] = *(const short8*)(Bp + r * BK + e);
      }
    BARRIER;
    __builtin_amdgcn_s_setprio(1);
    #pragma unroll
    for (int kk = 0; kk < 2; kk++)
      #pragma unroll
      for (int i = 0; i < 4; i++)
        #pragma unroll
        for (int j = 0; j < 2; j++)
          acc[i][j + 2] = __builtin_amdgcn_mfma_f32_16x16x32_bf16(afr[kk][i], bf1[kk][j], acc[i][j + 2], 0, 0, 0);
    __builtin_amdgcn_s_setprio(0);
    BARRIER;
    // all B reads of buf[cur] complete across waves -> B slot free

    // ---- ph2: stage B(kt+2) into freed B[cur]; read A-hi (8); Q11 ----
    if (kt + 2 < NT) STAGE_B(kt + 2, cur);
    #pragma unroll
    for (int kk = 0; kk < 2; kk++)
      #pragma unroll
      for (int i = 0; i < 4; i++) {
        int r = wm * 128 + (i + 4) * 16 + l15;
        int e = (kk * 32 + g * 8) ^ ((r & 7) << 3);
        afr[kk][i] = *(const short8*)(Ap + r * BK + e);
      }
    BARRIER;
    __builtin_amdgcn_s_setprio(1);
    #pragma unroll
    for (int kk = 0; kk < 2; kk++)
      #pragma unroll
      for (int i = 0; i < 4; i++)
        #pragma unroll
        for (int j = 0; j < 2; j++)
          acc[i + 4][j + 2] = __builtin_amdgcn_mfma_f32_16x16x32_bf16(afr[kk][i], bf1[kk][j], acc[i + 4][j + 2], 0, 0, 0);
    __builtin_amdgcn_s_setprio(0);
    BARRIER;
    // all A reads of buf[cur] complete -> A slot free

    // ---- ph3: stage A(kt+2) into freed A[cur]; Q10 (regs only); tile-boundary wait ----
    if (kt + 2 < NT) STAGE_A(kt + 2, cur);
    __builtin_amdgcn_s_setprio(1);
    #pragma unroll
    for (int kk = 0; kk < 2; kk++)
      #pragma unroll
      for (int i = 0; i < 4; i++)
        #pragma unroll
        for (int j = 0; j < 2; j++)
          acc[i + 4][j] = __builtin_amdgcn_mfma_f32_16x16x32_bf16(afr[kk][i], bf0[kk][j], acc[i + 4][j], 0, 0, 0);
    __builtin_amdgcn_s_setprio(0);
    if (kt + 2 < NT) { VMCNT8; } else { VMCNT0; }   // newest 8 = kt+2's -> kt+1 resident
    BARRIER;

    cur ^= 1;
  }

  int r0 = tm * 256 + wm * 128;
  int c0 = tn * 256 + wn * 64;
  if (PHASE == 1) {
    u16* mid = (u16*)Cout + ((size_t)b << 20);
    #pragma unroll
    for (int i = 0; i < 8; i++)
      #pragma unroll
      for (int j = 0; j < 4; j++)
        #pragma unroll
        for (int r = 0; r < 4; r++) {
          int row = r0 + i * 16 + g * 4 + r;
          int col = c0 + j * 16 + l15;
          mid[(size_t)row * DD + col] = f2bf(gelu_f(acc[i][j][r]));
        }
  } else {
    float* out = (float*)Cout + ((size_t)b << 20);
    const u16* xb = resid + ((size_t)b << 20);
    #pragma unroll
    for (int i = 0; i < 8; i++)
      #pragma unroll
      for (int j = 0; j < 4; j++)
        #pragma unroll
        for (int r = 0; r < 4; r++) {
          int row = r0 + i * 16 + g * 4 + r;
          int col = c0 + j * 16 + l15;
          size_t idx = (size_t)row * DD + col;
          out[idx] = bf2f(xb[idx]) + acc[i][j][r];
        }
  }
}

extern "C" void kernel_launch(void* const* d_in, const int* in_sizes, int n_in,
                              void* d_out, int out_size, void* d_ws, size_t ws_size,
                              hipStream_t stream) {
  const float* x         = (const float*)d_in[0];
  const float* ada       = (const float*)d_in[1];
  const float* base_up   = (const float*)d_in[2];
  const float* base_down = (const float*)d_in[3];
  const float* gamma     = (const float*)d_in[4];
  const float* beta      = (const float*)d_in[5];
  const float* W1        = (const float*)d_in[6];
  const float* bias1     = (const float*)d_in[7];
  const float* W2        = (const float*)d_in[8];
  const float* bias2     = (const float*)d_in[9];
  float* out = (float*)d_out;
  char* ws = (char*)d_ws;

  float* c     = (float*)(ws);                 // 64 KB
  float* h     = (float*)(ws + 0x10000);       // 64 KB
  float* w     = (float*)(ws + 0x20000);       // 2 MB
  float* bdT   = (float*)(ws + 0x220000);      // 4 MB
  float* hpart = (float*)(ws + 0x620000);      // 2 MB
  u16*   xb    = (u16*)  (ws + 0x820000);      // 32 MB
  u16*   wtd   = (u16*)  (ws + 0x2820000);     // 32 MB
  u16*   wtu   = (u16*)  (ws + 0x4820000);     // 32 MB
  u16*   mid   = (u16*)  (ws + 0x6820000);     // 32 MB
  float* part  = (float*)(ws + 0x6820000);     // 32 MB, aliases mid (dead before gemm1)

  prep_kernel<<<dim3(9232), dim3(256), 0, stream>>>(x, xb, ada, gamma, beta, c, base_down, bdT);
  h_part_kernel<<<dim3(4, HSPLIT), dim3(256), 0, stream>>>(c, W1, hpart);
  h_reduce_kernel<<<dim3(64), dim3(256), 0, stream>>>(hpart, bias1, h);
  w_part_kernel<<<dim3(32, WSPLIT), dim3(256), 0, stream>>>(h, W2, part);
  w_reduce_kernel<<<dim3(2048), dim3(256), 0, stream>>>(part, bias2, w);
  fold_kernel<<<dim3(512, 16, 2), dim3(256), 0, stream>>>(bdT, base_up, w, wtd, wtu);
  gemm256_kernel<1><<<dim3(256), dim3(512), 0, stream>>>(xb, wtd, (const u16*)nullptr, (void*)mid);
  gemm256_kernel<2><<<dim3(256), dim3(512), 0, stream>>>(mid, wtu, xb, (void*)out);
}

// Round 7
// 252.158 us; speedup vs baseline: 2.1509x; 1.2375x over previous
//
#include <hip/hip_runtime.h>
#include <math.h>

#define DD 1024
#define NB 16
#define WSPLIT 16
#define HSPLIT 32

typedef unsigned short u16;
typedef __attribute__((ext_vector_type(8))) short short8;
typedef __attribute__((ext_vector_type(4))) float f32x4;

__device__ __forceinline__ float gelu_f(float x) {
  return 0.5f * x * (1.0f + erff(x * 0.70710678118654752440f));
}
__device__ __forceinline__ u16 f2bf(float f) {
  union { float f; unsigned u; } v; v.f = f;
  return (u16)((v.u + 0x7FFFu + ((v.u >> 16) & 1u)) >> 16);
}
__device__ __forceinline__ float bf2f(u16 b) {
  union { unsigned u; float f; } v; v.u = ((unsigned)b) << 16;
  return v.f;
}
__device__ __forceinline__ void gload_lds16(const u16* g, u16* l) {
  __builtin_amdgcn_global_load_lds(
      (const __attribute__((address_space(1))) void*)g,
      (__attribute__((address_space(3))) void*)l, 16, 0, 0);
}

#define VMCNT8   asm volatile("s_waitcnt vmcnt(8)" ::: "memory")
#define VMCNT0   asm volatile("s_waitcnt vmcnt(0)" ::: "memory")
#define BARRIER  asm volatile("s_barrier" ::: "memory")

// ---- fused prep: cvt x | LN | transpose+cvt base_down | cvt base_up ----
// [0,8192) cvt x->bf16 ; [8192,8208) LN ; [8208,9232) bdT bf16 ; [9232,9744) bu bf16
__launch_bounds__(256)
__global__ void prep_kernel(const float* __restrict__ x, u16* __restrict__ xb,
                            const float* __restrict__ ada, const float* __restrict__ gamma,
                            const float* __restrict__ beta, float* __restrict__ c,
                            const float* __restrict__ bdn, u16* __restrict__ bdTb,
                            const float* __restrict__ bu, u16* __restrict__ bub) {
  __shared__ float smem[1056];
  int bid = blockIdx.x;
  int t = threadIdx.x;
  if (bid < 8192) {
    size_t i = (size_t)bid * 256 + t;
    const float4* xf = (const float4*)x;
    float4 v0 = xf[i * 2], v1 = xf[i * 2 + 1];
    short8 o;
    o[0] = (short)f2bf(v0.x); o[1] = (short)f2bf(v0.y);
    o[2] = (short)f2bf(v0.z); o[3] = (short)f2bf(v0.w);
    o[4] = (short)f2bf(v1.x); o[5] = (short)f2bf(v1.y);
    o[6] = (short)f2bf(v1.z); o[7] = (short)f2bf(v1.w);
    *(short8*)(xb + i * 8) = o;
  } else if (bid < 8208) {
    int b = bid - 8192;
    const float* row = ada + b * DD;
    float s = 0.f, s2 = 0.f;
    for (int i = t; i < DD; i += 256) { float v = row[i]; s += v; s2 += v * v; }
    for (int off = 32; off; off >>= 1) { s += __shfl_down(s, off); s2 += __shfl_down(s2, off); }
    float* rs = smem; float* rs2 = smem + 4;
    int wave = t >> 6, lane = t & 63;
    if (lane == 0) { rs[wave] = s; rs2[wave] = s2; }
    __syncthreads();
    if (t == 0) {
      float a = 0.f, a2 = 0.f;
      for (int w = 0; w < 4; w++) { a += rs[w]; a2 += rs2[w]; }
      rs[0] = a * (1.0f / DD); rs2[0] = a2 * (1.0f / DD);
    }
    __syncthreads();
    float mu = rs[0];
    float var = rs2[0] - mu * mu;
    float inv = rsqrtf(var + 1e-5f);
    for (int i = t; i < DD; i += 256)
      c[b * DD + i] = (row[i] - mu) * inv * gamma[i] + beta[i];
  } else if (bid < 9232) {
    int t2 = bid - 8208;
    int bx = (t2 & 31) * 32, by = (t2 >> 5) * 32;
    float (*tile)[33] = (float(*)[33])smem;
    int tx = t & 31, ty = t >> 5;   // 32 x 8
    for (int r = ty; r < 32; r += 8) tile[r][tx] = bdn[(size_t)(by + r) * DD + bx + tx];
    __syncthreads();
    for (int r = ty; r < 32; r += 8)
      bdTb[(size_t)(bx + r) * DD + by + tx] = f2bf(tile[tx][r]);
  } else {
    size_t i = (size_t)(bid - 9232) * 256 + t;
    const float4* bf = (const float4*)bu;
    float4 v0 = bf[i * 2], v1 = bf[i * 2 + 1];
    short8 o;
    o[0] = (short)f2bf(v0.x); o[1] = (short)f2bf(v0.y);
    o[2] = (short)f2bf(v0.z); o[3] = (short)f2bf(v0.w);
    o[4] = (short)f2bf(v1.x); o[5] = (short)f2bf(v1.y);
    o[6] = (short)f2bf(v1.z); o[7] = (short)f2bf(v1.w);
    *(short8*)(bub + i * 8) = o;
  }
}

// ------- h partials: split-K over W1 (32 splits of 32) -------
__launch_bounds__(256)
__global__ void h_part_kernel(const float* __restrict__ c, const float* __restrict__ W1,
                              float* __restrict__ hpart) {
  int s = blockIdx.y;
  int j = blockIdx.x * 256 + threadIdx.x;
  int k0 = s * 32;
  __shared__ float cs[NB][32];
  for (int i = threadIdx.x; i < NB * 32; i += 256)
    cs[i >> 5][i & 31] = c[(size_t)(i >> 5) * DD + k0 + (i & 31)];
  __syncthreads();
  float acc[NB];
  #pragma unroll
  for (int b = 0; b < NB; b++) acc[b] = 0.f;
  #pragma unroll
  for (int al = 0; al < 32; al++) {
    float wv = W1[(size_t)(k0 + al) * DD + j];
    #pragma unroll
    for (int b = 0; b < NB; b++) acc[b] += cs[b][al] * wv;
  }
  #pragma unroll
  for (int b = 0; b < NB; b++)
    hpart[((size_t)s * NB + b) * DD + j] = acc[b];
}

// ------- h = gelu(sum_s hpart[s] + bias1) -------
__launch_bounds__(256)
__global__ void h_reduce_kernel(const float* __restrict__ hpart, const float* __restrict__ bias1,
                                float* __restrict__ h) {
  int idx = blockIdx.x * 256 + threadIdx.x;
  int j = idx & (DD - 1);
  float acc = bias1[j];
  #pragma unroll
  for (int s = 0; s < HSPLIT; s++) acc += hpart[(size_t)s * NB * DD + idx];
  h[idx] = gelu_f(acc);
}

// ------- w partials: split-K over W2 (16 splits of 64), float4 columns -------
__launch_bounds__(256)
__global__ void w_part_kernel(const float* __restrict__ h, const float* __restrict__ W2,
                              float* __restrict__ part) {
  int s = blockIdx.y;
  int j4 = blockIdx.x * 256 + threadIdx.x;
  int k0 = s * 64;
  int t = threadIdx.x;
  __shared__ float hl[NB][64];
  for (int i = t; i < NB * 64; i += 256) hl[i >> 6][i & 63] = h[(size_t)(i >> 6) * DD + k0 + (i & 63)];
  __syncthreads();
  float4 acc[NB];
  #pragma unroll
  for (int b = 0; b < NB; b++) acc[b] = float4{0.f, 0.f, 0.f, 0.f};
  const float4* W2v = (const float4*)W2;
  #pragma unroll 4
  for (int al = 0; al < 64; al++) {
    float4 wv = W2v[(size_t)(k0 + al) * 8192 + j4];
    #pragma unroll
    for (int b = 0; b < NB; b++) {
      float hb = hl[b][al];
      acc[b].x += hb * wv.x; acc[b].y += hb * wv.y;
      acc[b].z += hb * wv.z; acc[b].w += hb * wv.w;
    }
  }
  float4* pv = (float4*)part;
  #pragma unroll
  for (int b = 0; b < NB; b++)
    pv[((size_t)s * NB + b) * 8192 + j4] = acc[b];
}

// ------- w = sum_s part[s] + bias2 -------
__launch_bounds__(256)
__global__ void w_reduce_kernel(const float* __restrict__ part, const float* __restrict__ bias2,
                                float* __restrict__ w) {
  int idx = blockIdx.x * 256 + threadIdx.x;
  int j = idx & 32767;
  float acc = bias2[j];
  #pragma unroll
  for (int s = 0; s < WSPLIT; s++) acc += part[(size_t)s * NB * 32768 + idx];
  w[idx] = acc;
}

// ---- pack_lora: aext[b][t][0..63] = zero-pad8( src[b][t][:] @ w[b][aoff + d*8 + r] ),
//      bext[b][l][0..63] = zero-pad8( w[b][boff + l*8 + r] )   (all bf16)
// grid (17, 16): x<16 -> 64 rows of u each; x==16 -> bext
__launch_bounds__(256)
__global__ void pack_lora_kernel(const u16* __restrict__ src, const float* __restrict__ w,
                                 int aoff, int boff,
                                 u16* __restrict__ aext, u16* __restrict__ bext) {
  int b = blockIdx.y;
  const float* wb = w + (size_t)b * 32768;
  int t = threadIdx.x;
  short8 z = {};
  if (blockIdx.x < 16) {
    __shared__ float a2s[8192];   // 32 KB: col factor [d][r]
    for (int i = t; i < 8192; i += 256) a2s[i] = wb[aoff + i];
    __syncthreads();
    int row = blockIdx.x * 64 + (t >> 2);
    int q = t & 3;
    const u16* xr = src + ((size_t)b << 20) + (size_t)row * DD + q * 256;
    float acc[8] = {};
    #pragma unroll 4
    for (int kk = 0; kk < 32; kk++) {
      short8 xv = *(const short8*)(xr + kk * 8);
      #pragma unroll
      for (int e = 0; e < 8; e++) {
        float xf = bf2f((u16)xv[e]);
        int d = q * 256 + kk * 8 + e;
        #pragma unroll
        for (int r = 0; r < 8; r++) acc[r] += xf * a2s[d * 8 + r];
      }
    }
    #pragma unroll
    for (int r = 0; r < 8; r++) {
      acc[r] += __shfl_xor(acc[r], 1);
      acc[r] += __shfl_xor(acc[r], 2);
    }
    short8 ov = z;
    if (q == 0) {
      #pragma unroll
      for (int r = 0; r < 8; r++) ov[r] = (short)f2bf(acc[r]);
    }
    u16* orow = aext + ((size_t)b * 1024 + row) * 64 + q * 16;
    *(short8*)orow = ov;
    *(short8*)(orow + 8) = z;
  } else {
    for (int l = t; l < 1024; l += 256) {
      short8 ov;
      #pragma unroll
      for (int r = 0; r < 8; r++) ov[r] = (short)f2bf(wb[boff + l * 8 + r]);
      u16* orow = bext + ((size_t)b * 1024 + l) * 64;
      *(short8*)orow = ov;
      #pragma unroll
      for (int k = 1; k < 8; k++) *(short8*)(orow + k * 8) = z;
    }
  }
}

// ------- batched GEMM 256x256 tile, 8 waves, phased schedule, K = 1024 + 64(ext) -------
// C = A@B^T with shared B panel + per-batch rank-8 extension tile (NT=17).
// PHASE 1: gelu -> bf16 mid.  PHASE 2: resid + acc -> f32 out.
#define STAGE_A(KT, BUF) do { int kt_ = (KT);                                          \
    if (kt_ < 16) { int ks_ = kt_ * 64;                                                \
      _Pragma("unroll")                                                                \
      for (int c_ = 0; c_ < 4; c_++)                                                   \
        gload_lds16(Ab + (size_t)srow[c_] * DD + ks_ + se[c_], As[BUF] + ldsel[c_]);   \
    } else {                                                                           \
      _Pragma("unroll")                                                                \
      for (int c_ = 0; c_ < 4; c_++)                                                   \
        gload_lds16(Ae + (size_t)srow[c_] * 64 + se[c_], As[BUF] + ldsel[c_]);         \
    } } while (0)
#define STAGE_B(KT, BUF) do { int kt_ = (KT);                                          \
    if (kt_ < 16) { int ks_ = kt_ * 64;                                                \
      _Pragma("unroll")                                                                \
      for (int c_ = 0; c_ < 4; c_++)                                                   \
        gload_lds16(Bb + (size_t)srow[c_] * DD + ks_ + se[c_], Bs[BUF] + ldsel[c_]);   \
    } else {                                                                           \
      _Pragma("unroll")                                                                \
      for (int c_ = 0; c_ < 4; c_++)                                                   \
        gload_lds16(Be + (size_t)srow[c_] * 64 + se[c_], Bs[BUF] + ldsel[c_]);         \
    } } while (0)

template<int PHASE>
__launch_bounds__(512, 2)
__global__ void gemm256_kernel(const u16* __restrict__ A, const u16* __restrict__ BT,
                               const u16* __restrict__ Aext, const u16* __restrict__ Bext,
                               const u16* __restrict__ resid, void* __restrict__ Cout) {
  constexpr int BK = 64;
  constexpr int NT = 17;   // 16 main K-tiles + 1 rank-8 ext tile
  __shared__ __align__(16) u16 As[2][256 * BK];   // 64 KB
  __shared__ __align__(16) u16 Bs[2][256 * BK];   // 64 KB

  // XCD-aware decode: each XCD owns 2 whole batches (L2-resident panels).
  int orig = blockIdx.x;
  int logical = (orig & 7) * 32 + (orig >> 3);
  int b = logical >> 4;
  int tile = logical & 15;
  int tm = tile >> 2, tn = tile & 3;

  const u16* Ab = A + ((size_t)b << 20) + (size_t)(tm * 256) * DD;
  const u16* Bb = BT + (size_t)(tn * 256) * DD;                       // batch-shared
  const u16* Ae = Aext + ((size_t)b * 1024 + tm * 256) * 64;
  const u16* Be = Bext + ((size_t)b * 1024 + tn * 256) * 64;

  int t = threadIdx.x, lane = t & 63, g = lane >> 4, l15 = lane & 15;
  int wave = t >> 6;
  int wm = wave >> 2, wn = wave & 3;   // 2 x 4 wave grid; per-wave 128 x 64 output

  // staging map: linear LDS dest, pre-swizzled source (involution cancels on read)
  int srow[4], se[4], ldsel[4];
  #pragma unroll
  for (int c = 0; c < 4; c++) {
    int chunk = c * 512 + t;            // 0..2047 -> 32 KB
    srow[c] = chunk >> 3;               // row 0..255
    se[c] = ((chunk & 7) ^ (srow[c] & 7)) << 3;
    ldsel[c] = chunk * 8;               // element offset
  }

  f32x4 acc[8][4] = {};

  STAGE_A(0, 0); STAGE_B(0, 0);
  STAGE_A(1, 1); STAGE_B(1, 1);
  VMCNT8;   // tile 0 resident
  BARRIER;

  int cur = 0;
  #pragma unroll 1
  for (int kt = 0; kt < NT; kt++) {
    const u16* Ap = As[cur];
    const u16* Bp = Bs[cur];
    short8 afr[2][4], bf0[2][2], bf1[2][2];

    // ---- ph0: read A-lo (8) + B-lo (4); Q00 ----
    #pragma unroll
    for (int kk = 0; kk < 2; kk++) {
      #pragma unroll
      for (int i = 0; i < 4; i++) {
        int r = wm * 128 + i * 16 + l15;
        int e = (kk * 32 + g * 8) ^ ((r & 7) << 3);
        afr[kk][i] = *(const short8*)(Ap + r * BK + e);
      }
      #pragma unroll
      for (int j = 0; j < 2; j++) {
        int r = wn * 64 + j * 16 + l15;
        int e = (kk * 32 + g * 8) ^ ((r & 7) << 3);
        bf0[kk][j] = *(const short8*)(Bp + r * BK + e);
      }
    }
    BARRIER;
    __builtin_amdgcn_s_setprio(1);
    #pragma unroll
    for (int kk = 0; kk < 2; kk++)
      #pragma unroll
      for (int i = 0; i < 4; i++)
        #pragma unroll
        for (int j = 0; j < 2; j++)
          acc[i][j] = __builtin_amdgcn_mfma_f32_16x16x32_bf16(afr[kk][i], bf0[kk][j], acc[i][j], 0, 0, 0);
    __builtin_amdgcn_s_setprio(0);
    BARRIER;

    // ---- ph1: read B-hi (4); Q01 ----
    #pragma unroll
    for (int kk = 0; kk < 2; kk++)
      #pragma unroll
      for (int j = 0; j < 2; j++) {
        int r = wn * 64 + (j + 2) * 16 + l15;
        int e = (kk * 32 + g * 8) ^ ((r & 7) << 3);
        bf1[kk][j] = *(const short8*)(Bp + r * BK + e);
      }
    BARRIER;
    __builtin_amdgcn_s_setprio(1);
    #pragma unroll
    for (int kk = 0; kk < 2; kk++)
      #pragma unroll
      for (int i = 0; i < 4; i++)
        #pragma unroll
        for (int j = 0; j < 2; j++)
          acc[i][j + 2] = __builtin_amdgcn_mfma_f32_16x16x32_bf16(afr[kk][i], bf1[kk][j], acc[i][j + 2], 0, 0, 0);
    __builtin_amdgcn_s_setprio(0);
    BARRIER;
    // all B reads of buf[cur] complete across waves -> B slot free

    // ---- ph2: stage B(kt+2) into freed B[cur]; read A-hi (8); Q11 ----
    if (kt + 2 < NT) STAGE_B(kt + 2, cur);
    #pragma unroll
    for (int kk = 0; kk < 2; kk++)
      #pragma unroll
      for (int i = 0; i < 4; i++) {
        int r = wm * 128 + (i + 4) * 16 + l15;
        int e = (kk * 32 + g * 8) ^ ((r & 7) << 3);
        afr[kk][i] = *(const short8*)(Ap + r * BK + e);
      }
    BARRIER;
    __builtin_amdgcn_s_setprio(1);
    #pragma unroll
    for (int kk = 0; kk < 2; kk++)
      #pragma unroll
      for (int i = 0; i < 4; i++)
        #pragma unroll
        for (int j = 0; j < 2; j++)
          acc[i + 4][j + 2] = __builtin_amdgcn_mfma_f32_16x16x32_bf16(afr[kk][i], bf1[kk][j], acc[i + 4][j + 2], 0, 0, 0);
    __builtin_amdgcn_s_setprio(0);
    BARRIER;
    // all A reads of buf[cur] complete -> A slot free

    // ---- ph3: stage A(kt+2) into freed A[cur]; Q10 (regs only); tile-boundary wait ----
    if (kt + 2 < NT) STAGE_A(kt + 2, cur);
    __builtin_amdgcn_s_setprio(1);
    #pragma unroll
    for (int kk = 0; kk < 2; kk++)
      #pragma unroll
      for (int i = 0; i < 4; i++)
        #pragma unroll
        for (int j = 0; j < 2; j++)
          acc[i + 4][j] = __builtin_amdgcn_mfma_f32_16x16x32_bf16(afr[kk][i], bf0[kk][j], acc[i + 4][j], 0, 0, 0);
    __builtin_amdgcn_s_setprio(0);
    if (kt + 2 < NT) { VMCNT8; } else { VMCNT0; }   // newest 8 = kt+2's -> kt+1 resident
    BARRIER;

    cur ^= 1;
  }

  int r0 = tm * 256 + wm * 128;
  int c0 = tn * 256 + wn * 64;
  if (PHASE == 1) {
    u16* mid = (u16*)Cout + ((size_t)b << 20);
    #pragma unroll
    for (int i = 0; i < 8; i++)
      #pragma unroll
      for (int j = 0; j < 4; j++)
        #pragma unroll
        for (int r = 0; r < 4; r++) {
          int row = r0 + i * 16 + g * 4 + r;
          int col = c0 + j * 16 + l15;
          mid[(size_t)row * DD + col] = f2bf(gelu_f(acc[i][j][r]));
        }
  } else {
    float* out = (float*)Cout + ((size_t)b << 20);
    const u16* xb = resid + ((size_t)b << 20);
    #pragma unroll
    for (int i = 0; i < 8; i++)
      #pragma unroll
      for (int j = 0; j < 4; j++)
        #pragma unroll
        for (int r = 0; r < 4; r++) {
          int row = r0 + i * 16 + g * 4 + r;
          int col = c0 + j * 16 + l15;
          size_t idx = (size_t)row * DD + col;
          out[idx] = bf2f(xb[idx]) + acc[i][j][r];
        }
  }
}

extern "C" void kernel_launch(void* const* d_in, const int* in_sizes, int n_in,
                              void* d_out, int out_size, void* d_ws, size_t ws_size,
                              hipStream_t stream) {
  const float* x         = (const float*)d_in[0];
  const float* ada       = (const float*)d_in[1];
  const float* base_up   = (const float*)d_in[2];
  const float* base_down = (const float*)d_in[3];
  const float* gamma     = (const float*)d_in[4];
  const float* beta      = (const float*)d_in[5];
  const float* W1        = (const float*)d_in[6];
  const float* bias1     = (const float*)d_in[7];
  const float* W2        = (const float*)d_in[8];
  const float* bias2     = (const float*)d_in[9];
  float* out = (float*)d_out;
  char* ws = (char*)d_ws;

  float* c     = (float*)(ws);                 // 64 KB
  float* h     = (float*)(ws + 0x10000);       // 64 KB
  float* w     = (float*)(ws + 0x20000);       // 2 MB
  u16*   bdTb  = (u16*)  (ws + 0x220000);      // 2 MB  (base_down^T bf16, shared)
  u16*   bub   = (u16*)  (ws + 0x420000);      // 2 MB  (base_up bf16, shared)
  float* hpart = (float*)(ws + 0x620000);      // 2 MB
  u16*   xb    = (u16*)  (ws + 0x820000);      // 32 MB
  u16*   uext  = (u16*)  (ws + 0x2820000);     // 2 MB  (x@a2, zero-padded to K=64)
  u16*   b2ext = (u16*)  (ws + 0x2A20000);     // 2 MB
  u16*   vext  = (u16*)  (ws + 0x2C20000);     // 2 MB  (mid@b1)
  u16*   a1ext = (u16*)  (ws + 0x2E20000);     // 2 MB
  u16*   mid   = (u16*)  (ws + 0x3020000);     // 32 MB
  float* part  = (float*)(ws + 0x3020000);     // 32 MB, aliases mid (dead before gemm1)

  prep_kernel<<<dim3(9744), dim3(256), 0, stream>>>(x, xb, ada, gamma, beta, c,
                                                    base_down, bdTb, base_up, bub);
  h_part_kernel<<<dim3(4, HSPLIT), dim3(256), 0, stream>>>(c, W1, hpart);
  h_reduce_kernel<<<dim3(64), dim3(256), 0, stream>>>(hpart, bias1, h);
  w_part_kernel<<<dim3(32, WSPLIT), dim3(256), 0, stream>>>(h, W2, part);
  w_reduce_kernel<<<dim3(2048), dim3(256), 0, stream>>>(part, bias2, w);
  pack_lora_kernel<<<dim3(17, 16), dim3(256), 0, stream>>>(xb, w, 16384, 24576, uext, b2ext);
  gemm256_kernel<1><<<dim3(256), dim3(512), 0, stream>>>(xb, bdTb, uext, b2ext,
                                                         (const u16*)nullptr, (void*)mid);
  pack_lora_kernel<<<dim3(17, 16), dim3(256), 0, stream>>>(mid, w, 8192, 0, vext, a1ext);
  gemm256_kernel<2><<<dim3(256), dim3(512), 0, stream>>>(mid, bub, vext, a1ext, xb, (void*)out);
}